// Round 1
// baseline (1254.704 us; speedup 1.0000x reference)
//
#include <hip/hip_runtime.h>
#include <math.h>

#define NEG 0.2f

static __device__ __forceinline__ float lrelu(float x){ return x > 0.f ? x : NEG*x; }

// ---------------- utility ----------------
__global__ void k_zero(int* __restrict__ p, int n){
  int i = blockIdx.x*blockDim.x + threadIdx.x;
  if (i < n) p[i] = 0;
}

// detect int64 vs int32 edge_index layout: if high words (odd int32) of first
// 64 entries are all zero -> int64. (int32 layout would have random values there)
__global__ void k_flag(const int* __restrict__ u, int* __restrict__ flag){
  if (threadIdx.x == 0 && blockIdx.x == 0) {
    int z = 1;
    for (int e = 0; e < 64; ++e) if (u[2*e+1] != 0) { z = 0; break; }
    *flag = z;
  }
}

// ---------------- CSR build ----------------
__global__ void k_count(const int* __restrict__ u, const int* __restrict__ flag,
                        int* __restrict__ cnt, int E){
  int e = blockIdx.x*blockDim.x + threadIdx.x;
  if (e >= E) return;
  int dst = (*flag) ? u[2*(E+e)] : u[E+e];
  atomicAdd(&cnt[dst], 1);
}

// block scans 1024 counts (256 thr x 4), writes within-block exclusive scan + block total
__global__ __launch_bounds__(256) void k_scan1(const int* __restrict__ cnt,
    int* __restrict__ ro, int* __restrict__ bsum, int n){
  int t = threadIdx.x;
  int base = blockIdx.x*1024 + t*4;
  int v0 = (base+0 < n) ? cnt[base+0] : 0;
  int v1 = (base+1 < n) ? cnt[base+1] : 0;
  int v2 = (base+2 < n) ? cnt[base+2] : 0;
  int v3 = (base+3 < n) ? cnt[base+3] : 0;
  int s = v0+v1+v2+v3;
  int lane = t & 63, w = t >> 6;
  int inc = s;
  for (int off = 1; off < 64; off <<= 1) {
    int tm = __shfl_up(inc, off);
    if (lane >= off) inc += tm;
  }
  __shared__ int wsum[4];
  if (lane == 63) wsum[w] = inc;
  __syncthreads();
  int wpre = 0;
  for (int k = 0; k < 4; ++k) if (k < w) wpre += wsum[k];
  int run = wpre + inc - s;
  if (base+0 < n) ro[base+0] = run; run += v0;
  if (base+1 < n) ro[base+1] = run; run += v1;
  if (base+2 < n) ro[base+2] = run; run += v2;
  if (base+3 < n) ro[base+3] = run; run += v3;
  if (t == 255) bsum[blockIdx.x] = run;
}

// single-wave scan of block totals (nb <= 128)
__global__ void k_scan2(int* __restrict__ bsum, int nb){
  int lane = threadIdx.x;
  int carry = 0;
  for (int b = 0; b < nb; b += 64) {
    int i = b + lane;
    int v = (i < nb) ? bsum[i] : 0;
    int inc = v;
    for (int off = 1; off < 64; off <<= 1) {
      int t = __shfl_up(inc, off);
      if (lane >= off) inc += t;
    }
    if (i < nb) bsum[i] = carry + inc - v;
    carry += __shfl(inc, 63);
  }
}

__global__ void k_scan3(int* __restrict__ ro, int* __restrict__ cur,
                        const int* __restrict__ bsum, int n, int E){
  int i = blockIdx.x*blockDim.x + threadIdx.x;
  if (i < n) {
    int v = ro[i] + bsum[i >> 10];
    ro[i] = v; cur[i] = v;
  }
  if (i == 0) ro[n] = E;
}

__global__ void k_fill(const int* __restrict__ u, const int* __restrict__ flag,
                       int* __restrict__ cur, int* __restrict__ csr, int E){
  int e = blockIdx.x*blockDim.x + threadIdx.x;
  if (e >= E) return;
  int src, dst;
  if (*flag) { src = u[2*e]; dst = u[2*(E+e)]; }
  else       { src = u[e];   dst = u[E+e]; }
  int p = atomicAdd(&cur[dst], 1);
  csr[p] = src;
}

// ---------------- layer 1 projection: h1 = x @ W1, attention logit halves ----------------
// one wave per 4 nodes; W1 (512x64 f32 = 128KB) staged in LDS; x via scalar loads
__global__ __launch_bounds__(256) void k_proj1(const float* __restrict__ x,
    const float* __restrict__ W1, const float* __restrict__ a1s_g, const float* __restrict__ a1d_g,
    float* __restrict__ h1, float* __restrict__ al1s, float* __restrict__ al1d, int n){
  __shared__ float ws[512*64];
  {
    const float4* s4 = (const float4*)W1;
    float4* d4 = (float4*)ws;
    for (int i = threadIdx.x; i < 512*64/4; i += 256) d4[i] = s4[i];
  }
  __syncthreads();
  int lane = threadIdx.x & 63;
  float a_s = a1s_g[lane];   // a1_src[h][d], lane = h*8+d
  float a_d = a1d_g[lane];
  int wid = blockIdx.x*4 + (threadIdx.x >> 6);
  int nw  = gridDim.x*4;
  int ng  = (n + 3) >> 2;
  for (int g = wid; g < ng; g += nw) {
    int n0 = __builtin_amdgcn_readfirstlane(g) * 4;
    const float* x0 = x + (size_t)n0*512;
    const float* x1 = x0 + 512;
    const float* x2 = x0 + 1024;
    const float* x3 = x0 + 1536;
    float acc0 = 0.f, acc1 = 0.f, acc2 = 0.f, acc3 = 0.f;
    for (int f = 0; f < 512; ++f) {
      float w = ws[f*64 + lane];
      acc0 = fmaf(x0[f], w, acc0);
      acc1 = fmaf(x1[f], w, acc1);
      acc2 = fmaf(x2[f], w, acc2);
      acc3 = fmaf(x3[f], w, acc3);
    }
    float accs[4] = {acc0, acc1, acc2, acc3};
    #pragma unroll
    for (int t = 0; t < 4; ++t) {
      int node = n0 + t;
      if (node >= n) break;
      float a = accs[t];
      h1[(size_t)node*64 + lane] = a;
      float vs = a * a_s, vd = a * a_d;
      vs += __shfl_xor(vs, 1); vs += __shfl_xor(vs, 2); vs += __shfl_xor(vs, 4);
      vd += __shfl_xor(vd, 1); vd += __shfl_xor(vd, 2); vd += __shfl_xor(vd, 4);
      if ((lane & 7) == 0) {
        al1s[node*8 + (lane >> 3)] = vs;
        al1d[node*8 + (lane >> 3)] = vd;
      }
    }
  }
}

// ---------------- layer 1 aggregation + ELU ----------------
// one wave per dst node; lane = h*8+d. Single pass: out = (sum ex*h1[src]) / (sum ex)
__global__ __launch_bounds__(256) void k_agg1(const int* __restrict__ ro,
    const int* __restrict__ csr, const float* __restrict__ al1s,
    const float* __restrict__ al1d, const float* __restrict__ h1,
    float* __restrict__ h1b, int n){
  int wid = blockIdx.x*4 + (threadIdx.x >> 6);
  if (wid >= n) return;
  int node = __builtin_amdgcn_readfirstlane(wid);
  int lane = threadIdx.x & 63;
  int h = lane >> 3;
  int beg = ro[node], end = ro[node+1];
  float ald = al1d[node*8 + h];
  float s = 0.f, acc = 0.f;
  int src_next = (beg < end) ? csr[beg] : 0;
  for (int i = beg; i < end; ++i) {
    int src = src_next;
    if (i + 1 < end) src_next = csr[i+1];
    float e = al1s[src*8 + h] + ald;
    e = lrelu(e);
    float ex = __expf(e);
    s += ex;
    acc = fmaf(h1[(size_t)src*64 + lane], ex, acc);
  }
  float v = acc / (s + 1e-16f);
  v = v > 0.f ? v : expm1f(v);   // ELU
  h1b[(size_t)node*64 + lane] = v;
}

// ---------------- layer 2 projection: h2 = elu(h1agg) @ W2, logit halves ----------------
__global__ __launch_bounds__(256) void k_proj2(const float* __restrict__ h1b,
    const float* __restrict__ W2, const float* __restrict__ a2s_g, const float* __restrict__ a2d_g,
    float* __restrict__ h2, float* __restrict__ al2s, float* __restrict__ al2d, int n){
  __shared__ float w[64*16];
  __shared__ float a2sv[16], a2dv[16];
  for (int i = threadIdx.x; i < 1024; i += 256) w[i] = W2[i];
  if (threadIdx.x < 16) { a2sv[threadIdx.x] = a2s_g[threadIdx.x]; a2dv[threadIdx.x] = a2d_g[threadIdx.x]; }
  __syncthreads();
  int c = threadIdx.x & 15;
  int nid = blockIdx.x*16 + (threadIdx.x >> 4);
  if (nid >= n) return;
  const float* row = h1b + (size_t)nid*64;
  float acc = 0.f;
  #pragma unroll
  for (int k0 = 0; k0 < 64; k0 += 4) {
    float4 r = *(const float4*)(row + k0);
    acc = fmaf(r.x, w[(k0+0)*16 + c], acc);
    acc = fmaf(r.y, w[(k0+1)*16 + c], acc);
    acc = fmaf(r.z, w[(k0+2)*16 + c], acc);
    acc = fmaf(r.w, w[(k0+3)*16 + c], acc);
  }
  h2[(size_t)nid*16 + c] = acc;
  float vs = acc * a2sv[c], vd = acc * a2dv[c];
  vs += __shfl_xor(vs, 1); vs += __shfl_xor(vs, 2); vs += __shfl_xor(vs, 4); vs += __shfl_xor(vs, 8);
  vd += __shfl_xor(vd, 1); vd += __shfl_xor(vd, 2); vd += __shfl_xor(vd, 4); vd += __shfl_xor(vd, 8);
  if (c == 0) { al2s[nid] = vs; al2d[nid] = vd; }
}

// ---------------- layer 2 aggregation + log_softmax ----------------
// one wave per dst node; lane = j*16+c (j = edge slot, c = class)
__global__ __launch_bounds__(256) void k_agg2(const int* __restrict__ ro,
    const int* __restrict__ csr, const float* __restrict__ al2s,
    const float* __restrict__ al2d, const float* __restrict__ h2,
    float* __restrict__ out, int n){
  int wid = blockIdx.x*4 + (threadIdx.x >> 6);
  if (wid >= n) return;
  int node = __builtin_amdgcn_readfirstlane(wid);
  int lane = threadIdx.x & 63;
  int j = lane >> 4, c = lane & 15;
  int beg = ro[node], end = ro[node+1];
  float ald = al2d[node];
  float sp = 0.f, acc = 0.f;
  for (int i = beg + j; i < end; i += 4) {
    int src = csr[i];
    float e = lrelu(al2s[src] + ald);
    float ex = __expf(e);
    sp += ex;
    acc = fmaf(ex, h2[(size_t)src*16 + c], acc);
  }
  sp  += __shfl_xor(sp, 16);  sp  += __shfl_xor(sp, 32);
  acc += __shfl_xor(acc, 16); acc += __shfl_xor(acc, 32);
  float v = acc / (sp + 1e-16f);
  // log_softmax over the 16 classes (one 16-lane group)
  float m = v;
  m = fmaxf(m, __shfl_xor(m, 1)); m = fmaxf(m, __shfl_xor(m, 2));
  m = fmaxf(m, __shfl_xor(m, 4)); m = fmaxf(m, __shfl_xor(m, 8));
  float l = v - m;
  float se = __expf(l);
  se += __shfl_xor(se, 1); se += __shfl_xor(se, 2);
  se += __shfl_xor(se, 4); se += __shfl_xor(se, 8);
  float res = l - logf(se);
  if (j == 0) out[(size_t)node*16 + c] = res;
}

// ---------------- host ----------------
static inline size_t alignup(size_t x){ return (x + 255) & ~(size_t)255; }

extern "C" void kernel_launch(void* const* d_in, const int* in_sizes, int n_in,
                              void* d_out, int out_size, void* d_ws, size_t ws_size,
                              hipStream_t stream){
  const float* x   = (const float*)d_in[0];
  const int*   ei  = (const int*)  d_in[1];
  const float* W1  = (const float*)d_in[2];
  const float* a1s = (const float*)d_in[3];
  const float* a1d = (const float*)d_in[4];
  const float* W2  = (const float*)d_in[5];
  const float* a2s = (const float*)d_in[6];
  const float* a2d = (const float*)d_in[7];
  float* out = (float*)d_out;

  const int n = in_sizes[0] / 512;   // 100000
  const int E = in_sizes[1] / 2;     // 3200000

  // workspace carve (~79 MB)
  char* w = (char*)d_ws;
  float* h1   = (float*)w; w += alignup((size_t)n*64*4);
  float* h1b  = (float*)w; w += alignup((size_t)n*64*4);
  float* al1s_ = (float*)w; w += alignup((size_t)n*8*4);
  float* al1d_ = (float*)w; w += alignup((size_t)n*8*4);
  float* h2   = (float*)w; w += alignup((size_t)n*16*4);
  float* al2s_ = (float*)w; w += alignup((size_t)n*4);
  float* al2d_ = (float*)w; w += alignup((size_t)n*4);
  int* cnt    = (int*)w;   w += alignup((size_t)n*4);
  int* ro     = (int*)w;   w += alignup((size_t)(n+1)*4);
  int* cur    = (int*)w;   w += alignup((size_t)n*4);
  int* csr    = (int*)w;   w += alignup((size_t)E*4);
  int* bsum   = (int*)w;   w += alignup(512*4);
  int* flag   = (int*)w;   w += alignup(64);

  const int nb_scan = (n + 1023) / 1024;

  k_zero<<<(n+255)/256, 256, 0, stream>>>(cnt, n);
  k_flag<<<1, 64, 0, stream>>>(ei, flag);
  k_count<<<(E+255)/256, 256, 0, stream>>>(ei, flag, cnt, E);
  k_scan1<<<nb_scan, 256, 0, stream>>>(cnt, ro, bsum, n);
  k_scan2<<<1, 64, 0, stream>>>(bsum, nb_scan);
  k_scan3<<<(n+255)/256, 256, 0, stream>>>(ro, cur, bsum, n, E);
  k_fill<<<(E+255)/256, 256, 0, stream>>>(ei, flag, cur, csr, E);

  k_proj1<<<256, 256, 0, stream>>>(x, W1, a1s, a1d, h1, al1s_, al1d_, n);
  k_agg1<<<(n+3)/4, 256, 0, stream>>>(ro, csr, al1s_, al1d_, h1, h1b, n);
  k_proj2<<<(n+15)/16, 256, 0, stream>>>(h1b, W2, a2s, a2d, h2, al2s_, al2d_, n);
  k_agg2<<<(n+3)/4, 256, 0, stream>>>(ro, csr, al2s_, al2d_, h2, out, n);
}

// Round 2
// 945.532 us; speedup vs baseline: 1.3270x; 1.3270x over previous
//
#include <hip/hip_runtime.h>
#include <math.h>

#define NEG 0.2f

static __device__ __forceinline__ float lrelu(float x){ return x > 0.f ? x : NEG*x; }

// ---------------- utility ----------------
__global__ void k_zero(int* __restrict__ p, int n){
  int i = blockIdx.x*blockDim.x + threadIdx.x;
  if (i < n) p[i] = 0;
}

// detect int64 vs int32 edge_index layout: if high words (odd int32) of first
// 64 entries are all zero -> int64. (int32 layout would have random values there)
__global__ void k_flag(const int* __restrict__ u, int* __restrict__ flag){
  if (threadIdx.x == 0 && blockIdx.x == 0) {
    int z = 1;
    for (int e = 0; e < 64; ++e) if (u[2*e+1] != 0) { z = 0; break; }
    *flag = z;
  }
}

// ---------------- CSR build ----------------
__global__ void k_count(const int* __restrict__ u, const int* __restrict__ flag,
                        int* __restrict__ cnt, int E){
  int e = blockIdx.x*blockDim.x + threadIdx.x;
  if (e >= E) return;
  int dst = (*flag) ? u[2*(E+e)] : u[E+e];
  atomicAdd(&cnt[dst], 1);
}

// block scans 1024 counts (256 thr x 4), writes within-block exclusive scan + block total
__global__ __launch_bounds__(256) void k_scan1(const int* __restrict__ cnt,
    int* __restrict__ ro, int* __restrict__ bsum, int n){
  int t = threadIdx.x;
  int base = blockIdx.x*1024 + t*4;
  int v0 = (base+0 < n) ? cnt[base+0] : 0;
  int v1 = (base+1 < n) ? cnt[base+1] : 0;
  int v2 = (base+2 < n) ? cnt[base+2] : 0;
  int v3 = (base+3 < n) ? cnt[base+3] : 0;
  int s = v0+v1+v2+v3;
  int lane = t & 63, w = t >> 6;
  int inc = s;
  for (int off = 1; off < 64; off <<= 1) {
    int tm = __shfl_up(inc, off);
    if (lane >= off) inc += tm;
  }
  __shared__ int wsum[4];
  if (lane == 63) wsum[w] = inc;
  __syncthreads();
  int wpre = 0;
  for (int k = 0; k < 4; ++k) if (k < w) wpre += wsum[k];
  int run = wpre + inc - s;
  if (base+0 < n) ro[base+0] = run; run += v0;
  if (base+1 < n) ro[base+1] = run; run += v1;
  if (base+2 < n) ro[base+2] = run; run += v2;
  if (base+3 < n) ro[base+3] = run; run += v3;
  if (t == 255) bsum[blockIdx.x] = run;
}

// single-wave scan of block totals (nb <= 128)
__global__ void k_scan2(int* __restrict__ bsum, int nb){
  int lane = threadIdx.x;
  int carry = 0;
  for (int b = 0; b < nb; b += 64) {
    int i = b + lane;
    int v = (i < nb) ? bsum[i] : 0;
    int inc = v;
    for (int off = 1; off < 64; off <<= 1) {
      int t = __shfl_up(inc, off);
      if (lane >= off) inc += t;
    }
    if (i < nb) bsum[i] = carry + inc - v;
    carry += __shfl(inc, 63);
  }
}

__global__ void k_scan3(int* __restrict__ ro, int* __restrict__ cur,
                        const int* __restrict__ bsum, int n, int E){
  int i = blockIdx.x*blockDim.x + threadIdx.x;
  if (i < n) {
    int v = ro[i] + bsum[i >> 10];
    ro[i] = v; cur[i] = v;
  }
  if (i == 0) ro[n] = E;
}

__global__ void k_fill(const int* __restrict__ u, const int* __restrict__ flag,
                       int* __restrict__ cur, int* __restrict__ csr, int E){
  int e = blockIdx.x*blockDim.x + threadIdx.x;
  if (e >= E) return;
  int src, dst;
  if (*flag) { src = u[2*e]; dst = u[2*(E+e)]; }
  else       { src = u[e];   dst = u[E+e]; }
  int p = atomicAdd(&cur[dst], 1);
  csr[p] = src;
}

// ---------------- layer 1 projection: h1 = x @ W1 (tiled GEMM) ----------------
// 64-node x 64-col tile per block, K chunked at 128.
// LDS: xs 32KB + ws 32KB = 64KB -> 2 blocks/CU (8 waves).
// Wave w handles nodes w*16..w*16+15 (local); lane = output col.
// Inner 4-k group: 4 ds_read_b32 (W, lane-consecutive, conflict-free)
//                + 16 ds_read_b128 (x, wave-uniform broadcast) + 64 FMA.
__global__ __launch_bounds__(256) void k_proj1(const float* __restrict__ x,
    const float* __restrict__ W1, const float* __restrict__ a1s_g, const float* __restrict__ a1d_g,
    float* __restrict__ h1, float* __restrict__ al1s, float* __restrict__ al1d, int n){
  __shared__ float xs[64*128];   // [node_local][kk]
  __shared__ float wl[128*64];   // [kk][c]
  const int tid = threadIdx.x;
  const int c = tid & 63;
  const int w = tid >> 6;
  const int n0 = blockIdx.x * 64;

  float a_s = a1s_g[c];   // a1_src[h][d], c = h*8+d
  float a_d = a1d_g[c];

  float acc[16];
  #pragma unroll
  for (int i = 0; i < 16; ++i) acc[i] = 0.f;

  for (int k0 = 0; k0 < 512; k0 += 128) {
    // stage: 2048 float4 each for x-tile and W-chunk, coalesced
    #pragma unroll
    for (int i = 0; i < 8; ++i) {
      int f4 = tid + i*256;           // 0..2047
      int row = f4 >> 5;              // 32 float4 per 128-float row
      int kk4 = f4 & 31;
      int node = n0 + row; if (node >= n) node = n - 1;
      float4 xv = *(const float4*)&x[(size_t)node*512 + k0 + kk4*4];
      float4 wv = *(const float4*)&W1[(size_t)k0*64 + f4*4];
      *(float4*)&xs[f4*4] = xv;
      *(float4*)&wl[f4*4] = wv;
    }
    __syncthreads();

    const float* xw = &xs[(w*16)*128];
    for (int kk = 0; kk < 128; kk += 4) {
      float w0 = wl[(kk+0)*64 + c];
      float w1 = wl[(kk+1)*64 + c];
      float w2 = wl[(kk+2)*64 + c];
      float w3 = wl[(kk+3)*64 + c];
      #pragma unroll
      for (int i = 0; i < 16; ++i) {
        float4 xv = *(const float4*)&xw[i*128 + kk];  // uniform -> broadcast
        acc[i] = fmaf(xv.x, w0, acc[i]);
        acc[i] = fmaf(xv.y, w1, acc[i]);
        acc[i] = fmaf(xv.z, w2, acc[i]);
        acc[i] = fmaf(xv.w, w3, acc[i]);
      }
    }
    __syncthreads();
  }

  // epilogue: write h1 + attention logit halves
  #pragma unroll
  for (int i = 0; i < 16; ++i) {
    int node = n0 + w*16 + i;
    if (node >= n) break;
    float a = acc[i];
    h1[(size_t)node*64 + c] = a;
    float vs = a * a_s, vd = a * a_d;
    vs += __shfl_xor(vs, 1); vs += __shfl_xor(vs, 2); vs += __shfl_xor(vs, 4);
    vd += __shfl_xor(vd, 1); vd += __shfl_xor(vd, 2); vd += __shfl_xor(vd, 4);
    if ((c & 7) == 0) {
      al1s[node*8 + (c >> 3)] = vs;
      al1d[node*8 + (c >> 3)] = vd;
    }
  }
}

// ---------------- layer 1 aggregation + ELU ----------------
// one wave per dst node; lane = h*8+d. Single pass: out = (sum ex*h1[src]) / (sum ex)
__global__ __launch_bounds__(256) void k_agg1(const int* __restrict__ ro,
    const int* __restrict__ csr, const float* __restrict__ al1s,
    const float* __restrict__ al1d, const float* __restrict__ h1,
    float* __restrict__ h1b, int n){
  int wid = blockIdx.x*4 + (threadIdx.x >> 6);
  if (wid >= n) return;
  int node = __builtin_amdgcn_readfirstlane(wid);
  int lane = threadIdx.x & 63;
  int h = lane >> 3;
  int beg = ro[node], end = ro[node+1];
  float ald = al1d[node*8 + h];
  float s = 0.f, acc = 0.f;
  int src_next = (beg < end) ? csr[beg] : 0;
  for (int i = beg; i < end; ++i) {
    int src = src_next;
    if (i + 1 < end) src_next = csr[i+1];
    float e = al1s[src*8 + h] + ald;
    e = lrelu(e);
    float ex = __expf(e);
    s += ex;
    acc = fmaf(h1[(size_t)src*64 + lane], ex, acc);
  }
  float v = acc / (s + 1e-16f);
  v = v > 0.f ? v : expm1f(v);   // ELU
  h1b[(size_t)node*64 + lane] = v;
}

// ---------------- layer 2 projection: h2 = elu(h1agg) @ W2, logit halves ----------------
__global__ __launch_bounds__(256) void k_proj2(const float* __restrict__ h1b,
    const float* __restrict__ W2, const float* __restrict__ a2s_g, const float* __restrict__ a2d_g,
    float* __restrict__ h2, float* __restrict__ al2s, float* __restrict__ al2d, int n){
  __shared__ float w[64*16];
  __shared__ float a2sv[16], a2dv[16];
  for (int i = threadIdx.x; i < 1024; i += 256) w[i] = W2[i];
  if (threadIdx.x < 16) { a2sv[threadIdx.x] = a2s_g[threadIdx.x]; a2dv[threadIdx.x] = a2d_g[threadIdx.x]; }
  __syncthreads();
  int c = threadIdx.x & 15;
  int nid = blockIdx.x*16 + (threadIdx.x >> 4);
  if (nid >= n) return;
  const float* row = h1b + (size_t)nid*64;
  float acc = 0.f;
  #pragma unroll
  for (int k0 = 0; k0 < 64; k0 += 4) {
    float4 r = *(const float4*)(row + k0);
    acc = fmaf(r.x, w[(k0+0)*16 + c], acc);
    acc = fmaf(r.y, w[(k0+1)*16 + c], acc);
    acc = fmaf(r.z, w[(k0+2)*16 + c], acc);
    acc = fmaf(r.w, w[(k0+3)*16 + c], acc);
  }
  h2[(size_t)nid*16 + c] = acc;
  float vs = acc * a2sv[c], vd = acc * a2dv[c];
  vs += __shfl_xor(vs, 1); vs += __shfl_xor(vs, 2); vs += __shfl_xor(vs, 4); vs += __shfl_xor(vs, 8);
  vd += __shfl_xor(vd, 1); vd += __shfl_xor(vd, 2); vd += __shfl_xor(vd, 4); vd += __shfl_xor(vd, 8);
  if (c == 0) { al2s[nid] = vs; al2d[nid] = vd; }
}

// ---------------- layer 2 aggregation + log_softmax ----------------
// one wave per dst node; lane = j*16+c (j = edge slot, c = class)
__global__ __launch_bounds__(256) void k_agg2(const int* __restrict__ ro,
    const int* __restrict__ csr, const float* __restrict__ al2s,
    const float* __restrict__ al2d, const float* __restrict__ h2,
    float* __restrict__ out, int n){
  int wid = blockIdx.x*4 + (threadIdx.x >> 6);
  if (wid >= n) return;
  int node = __builtin_amdgcn_readfirstlane(wid);
  int lane = threadIdx.x & 63;
  int j = lane >> 4, c = lane & 15;
  int beg = ro[node], end = ro[node+1];
  float ald = al2d[node];
  float sp = 0.f, acc = 0.f;
  for (int i = beg + j; i < end; i += 4) {
    int src = csr[i];
    float e = lrelu(al2s[src] + ald);
    float ex = __expf(e);
    sp += ex;
    acc = fmaf(ex, h2[(size_t)src*16 + c], acc);
  }
  sp  += __shfl_xor(sp, 16);  sp  += __shfl_xor(sp, 32);
  acc += __shfl_xor(acc, 16); acc += __shfl_xor(acc, 32);
  float v = acc / (sp + 1e-16f);
  // log_softmax over the 16 classes (one 16-lane group)
  float m = v;
  m = fmaxf(m, __shfl_xor(m, 1)); m = fmaxf(m, __shfl_xor(m, 2));
  m = fmaxf(m, __shfl_xor(m, 4)); m = fmaxf(m, __shfl_xor(m, 8));
  float l = v - m;
  float se = __expf(l);
  se += __shfl_xor(se, 1); se += __shfl_xor(se, 2);
  se += __shfl_xor(se, 4); se += __shfl_xor(se, 8);
  float res = l - logf(se);
  if (j == 0) out[(size_t)node*16 + c] = res;
}

// ---------------- host ----------------
static inline size_t alignup(size_t x){ return (x + 255) & ~(size_t)255; }

extern "C" void kernel_launch(void* const* d_in, const int* in_sizes, int n_in,
                              void* d_out, int out_size, void* d_ws, size_t ws_size,
                              hipStream_t stream){
  const float* x   = (const float*)d_in[0];
  const int*   ei  = (const int*)  d_in[1];
  const float* W1  = (const float*)d_in[2];
  const float* a1s = (const float*)d_in[3];
  const float* a1d = (const float*)d_in[4];
  const float* W2  = (const float*)d_in[5];
  const float* a2s = (const float*)d_in[6];
  const float* a2d = (const float*)d_in[7];
  float* out = (float*)d_out;

  const int n = in_sizes[0] / 512;   // 100000
  const int E = in_sizes[1] / 2;     // 3200000

  // workspace carve (~79 MB)
  char* w = (char*)d_ws;
  float* h1   = (float*)w; w += alignup((size_t)n*64*4);
  float* h1b  = (float*)w; w += alignup((size_t)n*64*4);
  float* al1s_ = (float*)w; w += alignup((size_t)n*8*4);
  float* al1d_ = (float*)w; w += alignup((size_t)n*8*4);
  float* h2   = (float*)w; w += alignup((size_t)n*16*4);
  float* al2s_ = (float*)w; w += alignup((size_t)n*4);
  float* al2d_ = (float*)w; w += alignup((size_t)n*4);
  int* cnt    = (int*)w;   w += alignup((size_t)n*4);
  int* ro     = (int*)w;   w += alignup((size_t)(n+1)*4);
  int* cur    = (int*)w;   w += alignup((size_t)n*4);
  int* csr    = (int*)w;   w += alignup((size_t)E*4);
  int* bsum   = (int*)w;   w += alignup(512*4);
  int* flag   = (int*)w;   w += alignup(64);

  const int nb_scan = (n + 1023) / 1024;

  k_zero<<<(n+255)/256, 256, 0, stream>>>(cnt, n);
  k_flag<<<1, 64, 0, stream>>>(ei, flag);
  k_count<<<(E+255)/256, 256, 0, stream>>>(ei, flag, cnt, E);
  k_scan1<<<nb_scan, 256, 0, stream>>>(cnt, ro, bsum, n);
  k_scan2<<<1, 64, 0, stream>>>(bsum, nb_scan);
  k_scan3<<<(n+255)/256, 256, 0, stream>>>(ro, cur, bsum, n, E);
  k_fill<<<(E+255)/256, 256, 0, stream>>>(ei, flag, cur, csr, E);

  k_proj1<<<(n+63)/64, 256, 0, stream>>>(x, W1, a1s, a1d, h1, al1s_, al1d_, n);
  k_agg1<<<(n+3)/4, 256, 0, stream>>>(ro, csr, al1s_, al1d_, h1, h1b, n);
  k_proj2<<<(n+15)/16, 256, 0, stream>>>(h1b, W2, a2s, a2d, h2, al2s_, al2d_, n);
  k_agg2<<<(n+3)/4, 256, 0, stream>>>(ro, csr, al2s_, al2d_, h2, out, n);
}

// Round 3
// 812.420 us; speedup vs baseline: 1.5444x; 1.1638x over previous
//
#include <hip/hip_runtime.h>
#include <math.h>

#define NEG 0.2f

typedef __attribute__((ext_vector_type(8))) short bf16x8;
typedef __attribute__((ext_vector_type(4))) float f32x4;

static __device__ __forceinline__ float lrelu(float x){ return x > 0.f ? x : NEG*x; }

// round-to-nearest-even fp32 -> bf16 split: v ~= hi + lo (each bf16)
static __device__ __forceinline__ void bsplit(float v, unsigned int& hi, unsigned int& lo){
  unsigned int u = __float_as_uint(v);
  unsigned int hb = (u + 0x7fffu + ((u >> 16) & 1u)) & 0xffff0000u;
  float hf = __uint_as_float(hb);
  float l = v - hf;
  unsigned int ul = __float_as_uint(l);
  hi = hb >> 16;
  lo = (ul + 0x7fffu + ((ul >> 16) & 1u)) >> 16;
}

// ---------------- utility ----------------
__global__ void k_zero(int* __restrict__ p, int n){
  int i = blockIdx.x*blockDim.x + threadIdx.x;
  if (i < n) p[i] = 0;
}

__global__ void k_flag(const int* __restrict__ u, int* __restrict__ flag){
  if (threadIdx.x == 0 && blockIdx.x == 0) {
    int z = 1;
    for (int e = 0; e < 64; ++e) if (u[2*e+1] != 0) { z = 0; break; }
    *flag = z;
  }
}

// ---------------- CSR build ----------------
__global__ void k_count(const int* __restrict__ u, const int* __restrict__ flag,
                        int* __restrict__ cnt, int E){
  int e = blockIdx.x*blockDim.x + threadIdx.x;
  if (e >= E) return;
  int dst = (*flag) ? u[2*(E+e)] : u[E+e];
  atomicAdd(&cnt[dst], 1);
}

__global__ __launch_bounds__(256) void k_scan1(const int* __restrict__ cnt,
    int* __restrict__ ro, int* __restrict__ bsum, int n){
  int t = threadIdx.x;
  int base = blockIdx.x*1024 + t*4;
  int v0 = (base+0 < n) ? cnt[base+0] : 0;
  int v1 = (base+1 < n) ? cnt[base+1] : 0;
  int v2 = (base+2 < n) ? cnt[base+2] : 0;
  int v3 = (base+3 < n) ? cnt[base+3] : 0;
  int s = v0+v1+v2+v3;
  int lane = t & 63, w = t >> 6;
  int inc = s;
  for (int off = 1; off < 64; off <<= 1) {
    int tm = __shfl_up(inc, off);
    if (lane >= off) inc += tm;
  }
  __shared__ int wsum[4];
  if (lane == 63) wsum[w] = inc;
  __syncthreads();
  int wpre = 0;
  for (int k = 0; k < 4; ++k) if (k < w) wpre += wsum[k];
  int run = wpre + inc - s;
  if (base+0 < n) ro[base+0] = run; run += v0;
  if (base+1 < n) ro[base+1] = run; run += v1;
  if (base+2 < n) ro[base+2] = run; run += v2;
  if (base+3 < n) ro[base+3] = run; run += v3;
  if (t == 255) bsum[blockIdx.x] = run;
}

__global__ void k_scan2(int* __restrict__ bsum, int nb){
  int lane = threadIdx.x;
  int carry = 0;
  for (int b = 0; b < nb; b += 64) {
    int i = b + lane;
    int v = (i < nb) ? bsum[i] : 0;
    int inc = v;
    for (int off = 1; off < 64; off <<= 1) {
      int t = __shfl_up(inc, off);
      if (lane >= off) inc += t;
    }
    if (i < nb) bsum[i] = carry + inc - v;
    carry += __shfl(inc, 63);
  }
}

__global__ void k_scan3(int* __restrict__ ro, int* __restrict__ cur,
                        const int* __restrict__ bsum, int n, int E){
  int i = blockIdx.x*blockDim.x + threadIdx.x;
  if (i < n) {
    int v = ro[i] + bsum[i >> 10];
    ro[i] = v; cur[i] = v;
  }
  if (i == 0) ro[n] = E;
}

__global__ void k_fill(const int* __restrict__ u, const int* __restrict__ flag,
                       int* __restrict__ cur, int* __restrict__ csr, int E){
  int e = blockIdx.x*blockDim.x + threadIdx.x;
  if (e >= E) return;
  int src, dst;
  if (*flag) { src = u[2*e]; dst = u[2*(E+e)]; }
  else       { src = u[e];   dst = u[E+e]; }
  int p = atomicAdd(&cur[dst], 1);
  csr[p] = src;
}

// ---------------- W1 prep: transpose + bf16 split -> wtH/wtL [64][512] ----------------
__global__ void k_wprep(const float* __restrict__ W1, unsigned short* __restrict__ wtH,
                        unsigned short* __restrict__ wtL){
  int i = blockIdx.x*256 + threadIdx.x;   // over 512*64
  if (i >= 512*64) return;
  int k = i >> 6, c = i & 63;
  unsigned int hi, lo;
  bsplit(W1[i], hi, lo);
  wtH[c*512 + k] = (unsigned short)hi;
  wtL[c*512 + k] = (unsigned short)lo;
}

// ---------------- layer 1 projection: h1 = x @ W1 via split-bf16 MFMA ----------------
// Block: 4 waves, 128 rows x 64 cols. K chunked at 64.
// LDS: xh/xl [128][64] bf16 (16KB ea) + wh/wl [64][64] bf16 (8KB ea) = 48KB -> 3 blk/CU.
// XOR swizzle byte ^= (row&7)<<4 makes all frag ds_read_b128 conflict-free.
// Frag layouts (gfx950 16x16x32): A row=l&15,k=8*(l>>4)+i; B col=l&15,k=8*(l>>4)+i;
// D col=l&15,row=4*(l>>4)+r (m89-verified).
__global__ __launch_bounds__(256, 3) void k_proj1(const float* __restrict__ x,
    const unsigned short* __restrict__ wtH, const unsigned short* __restrict__ wtL,
    const float* __restrict__ a1s_g, const float* __restrict__ a1d_g,
    float* __restrict__ h1, float* __restrict__ al1s, float* __restrict__ al1d, int n){
  __shared__ unsigned short lds[24576];   // 48KB
  char* const ldsb = (char*)lds;          // xh@0 xl@16384 wh@32768 wl@40960
  const int tid = threadIdx.x;
  const int lane = tid & 63;
  const int w = tid >> 6;
  const int l16 = lane & 15;
  const int lhi = lane >> 4;
  const int n0 = blockIdx.x * 128;

  float as_c[4], ad_c[4];
  #pragma unroll
  for (int f = 0; f < 4; ++f) { as_c[f] = a1s_g[16*f + l16]; ad_c[f] = a1d_g[16*f + l16]; }

  f32x4 acc[2][4];
  #pragma unroll
  for (int m = 0; m < 2; ++m)
    #pragma unroll
    for (int f = 0; f < 4; ++f) acc[m][f] = (f32x4){0.f,0.f,0.f,0.f};

  for (int k0 = 0; k0 < 512; k0 += 64) {
    // stage x chunk: 128 rows x 64 k, split into bf16 hi/lo
    #pragma unroll
    for (int i = 0; i < 8; ++i) {
      int f4 = tid + i*256;         // 0..2047
      int row = f4 >> 4;            // 16 float4 per 64-float row
      int k4 = f4 & 15;
      int node = n0 + row; if (node >= n) node = n - 1;
      float4 v = *(const float4*)&x[(size_t)node*512 + k0 + k4*4];
      unsigned int h0,h1_,h2,h3,l0,l1,l2,l3;
      bsplit(v.x, h0, l0); bsplit(v.y, h1_, l1);
      bsplit(v.z, h2, l2); bsplit(v.w, h3, l3);
      uint2 hp = make_uint2(h0 | (h1_<<16), h2 | (h3<<16));
      uint2 lp = make_uint2(l0 | (l1<<16),  l2 | (l3<<16));
      int byteoff = (row*128 + k4*8) ^ ((row & 7) << 4);
      *(uint2*)(ldsb + byteoff)         = hp;
      *(uint2*)(ldsb + 16384 + byteoff) = lp;
    }
    // stage W chunk: 64 cols x 64 k (already transposed+split in global)
    #pragma unroll
    for (int i = 0; i < 2; ++i) {
      int f8 = tid + i*256;         // 0..511
      int c = f8 >> 3;
      int kb = f8 & 7;              // 8 bf16 per b128
      uint4 hv = *(const uint4*)&wtH[c*512 + k0 + kb*8];
      uint4 lv = *(const uint4*)&wtL[c*512 + k0 + kb*8];
      int byteoff = (c*128 + kb*16) ^ ((c & 7) << 4);
      *(uint4*)(ldsb + 32768 + byteoff) = hv;
      *(uint4*)(ldsb + 40960 + byteoff) = lv;
    }
    __syncthreads();

    #pragma unroll
    for (int kk = 0; kk < 64; kk += 32) {
      bf16x8 ah[2], al_[2], bh[4], bl[4];
      #pragma unroll
      for (int m = 0; m < 2; ++m) {
        int row = 32*w + 16*m + l16;
        int byteoff = (row*128 + (kk + 8*lhi)*2) ^ ((row & 7) << 4);
        ah[m]  = *(const bf16x8*)(ldsb + byteoff);
        al_[m] = *(const bf16x8*)(ldsb + 16384 + byteoff);
      }
      #pragma unroll
      for (int f = 0; f < 4; ++f) {
        int c = 16*f + l16;
        int byteoff = (c*128 + (kk + 8*lhi)*2) ^ ((c & 7) << 4);
        bh[f] = *(const bf16x8*)(ldsb + 32768 + byteoff);
        bl[f] = *(const bf16x8*)(ldsb + 40960 + byteoff);
      }
      #pragma unroll
      for (int m = 0; m < 2; ++m)
        #pragma unroll
        for (int f = 0; f < 4; ++f) {
          acc[m][f] = __builtin_amdgcn_mfma_f32_16x16x32_bf16(ah[m],  bh[f], acc[m][f], 0, 0, 0);
          acc[m][f] = __builtin_amdgcn_mfma_f32_16x16x32_bf16(ah[m],  bl[f], acc[m][f], 0, 0, 0);
          acc[m][f] = __builtin_amdgcn_mfma_f32_16x16x32_bf16(al_[m], bh[f], acc[m][f], 0, 0, 0);
        }
    }
    __syncthreads();
  }

  // epilogue: h1 writes + per-head attention logit halves
  #pragma unroll
  for (int m = 0; m < 2; ++m) {
    #pragma unroll
    for (int r = 0; r < 4; ++r) {
      int node = n0 + 32*w + 16*m + 4*lhi + r;
      bool ok = (node < n);
      #pragma unroll
      for (int f = 0; f < 4; ++f) {
        float v = acc[m][f][r];
        if (ok) h1[(size_t)node*64 + 16*f + l16] = v;
        float vs = v * as_c[f], vd = v * ad_c[f];
        vs += __shfl_xor(vs, 1); vs += __shfl_xor(vs, 2); vs += __shfl_xor(vs, 4);
        vd += __shfl_xor(vd, 1); vd += __shfl_xor(vd, 2); vd += __shfl_xor(vd, 4);
        if (ok && (l16 & 7) == 0) {
          int head = 2*f + (l16 >> 3);
          al1s[node*8 + head] = vs;
          al1d[node*8 + head] = vd;
        }
      }
    }
  }
}

// ---------------- layer 1 aggregation + ELU (software-pipelined) ----------------
__global__ __launch_bounds__(256) void k_agg1(const int* __restrict__ ro,
    const int* __restrict__ csr, const float* __restrict__ al1s,
    const float* __restrict__ al1d, const float* __restrict__ h1,
    float* __restrict__ h1b, int n){
  int wid = blockIdx.x*4 + (threadIdx.x >> 6);
  if (wid >= n) return;
  int node = __builtin_amdgcn_readfirstlane(wid);
  int lane = threadIdx.x & 63;
  int h = lane >> 3;
  int beg = ro[node], end = ro[node+1];
  int m = end - beg;
  float ald = al1d[node*8 + h];
  float s = 0.f, acc = 0.f;
  int sA = (m > 0) ? csr[beg] : 0;
  int sB = (m > 1) ? csr[beg+1] : 0;
  float alA = al1s[sA*8 + h];
  float hvA = h1[(size_t)sA*64 + lane];
  for (int i = 0; i < m; ++i) {
    int sC = (i + 2 < m) ? csr[beg + i + 2] : 0;
    float alB = al1s[sB*8 + h];
    float hvB = h1[(size_t)sB*64 + lane];
    float e = alA + ald;
    e = e > 0.f ? e : NEG*e;
    float ex = __expf(e);
    s += ex;
    acc = fmaf(hvA, ex, acc);
    alA = alB; hvA = hvB; sB = sC;
  }
  float v = acc / (s + 1e-16f);
  v = v > 0.f ? v : expm1f(v);   // ELU
  h1b[(size_t)node*64 + lane] = v;
}

// ---------------- layer 2 projection ----------------
__global__ __launch_bounds__(256) void k_proj2(const float* __restrict__ h1b,
    const float* __restrict__ W2, const float* __restrict__ a2s_g, const float* __restrict__ a2d_g,
    float* __restrict__ h2, float* __restrict__ al2s, float* __restrict__ al2d, int n){
  __shared__ float w[64*16];
  __shared__ float a2sv[16], a2dv[16];
  for (int i = threadIdx.x; i < 1024; i += 256) w[i] = W2[i];
  if (threadIdx.x < 16) { a2sv[threadIdx.x] = a2s_g[threadIdx.x]; a2dv[threadIdx.x] = a2d_g[threadIdx.x]; }
  __syncthreads();
  int c = threadIdx.x & 15;
  int nid = blockIdx.x*16 + (threadIdx.x >> 4);
  if (nid >= n) return;
  const float* row = h1b + (size_t)nid*64;
  float acc = 0.f;
  #pragma unroll
  for (int k0 = 0; k0 < 64; k0 += 4) {
    float4 r = *(const float4*)(row + k0);
    acc = fmaf(r.x, w[(k0+0)*16 + c], acc);
    acc = fmaf(r.y, w[(k0+1)*16 + c], acc);
    acc = fmaf(r.z, w[(k0+2)*16 + c], acc);
    acc = fmaf(r.w, w[(k0+3)*16 + c], acc);
  }
  h2[(size_t)nid*16 + c] = acc;
  float vs = acc * a2sv[c], vd = acc * a2dv[c];
  vs += __shfl_xor(vs, 1); vs += __shfl_xor(vs, 2); vs += __shfl_xor(vs, 4); vs += __shfl_xor(vs, 8);
  vd += __shfl_xor(vd, 1); vd += __shfl_xor(vd, 2); vd += __shfl_xor(vd, 4); vd += __shfl_xor(vd, 8);
  if (c == 0) { al2s[nid] = vs; al2d[nid] = vd; }
}

// ---------------- layer 2 aggregation + log_softmax ----------------
__global__ __launch_bounds__(256) void k_agg2(const int* __restrict__ ro,
    const int* __restrict__ csr, const float* __restrict__ al2s,
    const float* __restrict__ al2d, const float* __restrict__ h2,
    float* __restrict__ out, int n){
  int wid = blockIdx.x*4 + (threadIdx.x >> 6);
  if (wid >= n) return;
  int node = __builtin_amdgcn_readfirstlane(wid);
  int lane = threadIdx.x & 63;
  int j = lane >> 4, c = lane & 15;
  int beg = ro[node], end = ro[node+1];
  float ald = al2d[node];
  float sp = 0.f, acc = 0.f;
  for (int i = beg + j; i < end; i += 4) {
    int src = csr[i];
    float e = lrelu(al2s[src] + ald);
    float ex = __expf(e);
    sp += ex;
    acc = fmaf(ex, h2[(size_t)src*16 + c], acc);
  }
  sp  += __shfl_xor(sp, 16);  sp  += __shfl_xor(sp, 32);
  acc += __shfl_xor(acc, 16); acc += __shfl_xor(acc, 32);
  float v = acc / (sp + 1e-16f);
  float mx = v;
  mx = fmaxf(mx, __shfl_xor(mx, 1)); mx = fmaxf(mx, __shfl_xor(mx, 2));
  mx = fmaxf(mx, __shfl_xor(mx, 4)); mx = fmaxf(mx, __shfl_xor(mx, 8));
  float l = v - mx;
  float se = __expf(l);
  se += __shfl_xor(se, 1); se += __shfl_xor(se, 2);
  se += __shfl_xor(se, 4); se += __shfl_xor(se, 8);
  float res = l - logf(se);
  if (j == 0) out[(size_t)node*16 + c] = res;
}

// ---------------- host ----------------
static inline size_t alignup(size_t x){ return (x + 255) & ~(size_t)255; }

extern "C" void kernel_launch(void* const* d_in, const int* in_sizes, int n_in,
                              void* d_out, int out_size, void* d_ws, size_t ws_size,
                              hipStream_t stream){
  const float* x   = (const float*)d_in[0];
  const int*   ei  = (const int*)  d_in[1];
  const float* W1  = (const float*)d_in[2];
  const float* a1s = (const float*)d_in[3];
  const float* a1d = (const float*)d_in[4];
  const float* W2  = (const float*)d_in[5];
  const float* a2s = (const float*)d_in[6];
  const float* a2d = (const float*)d_in[7];
  float* out = (float*)d_out;

  const int n = in_sizes[0] / 512;   // 100000
  const int E = in_sizes[1] / 2;     // 3200000

  char* w = (char*)d_ws;
  float* h1   = (float*)w; w += alignup((size_t)n*64*4);
  float* h1b  = (float*)w; w += alignup((size_t)n*64*4);
  float* al1s_ = (float*)w; w += alignup((size_t)n*8*4);
  float* al1d_ = (float*)w; w += alignup((size_t)n*8*4);
  float* h2   = (float*)w; w += alignup((size_t)n*16*4);
  float* al2s_ = (float*)w; w += alignup((size_t)n*4);
  float* al2d_ = (float*)w; w += alignup((size_t)n*4);
  int* cnt    = (int*)w;   w += alignup((size_t)n*4);
  int* ro     = (int*)w;   w += alignup((size_t)(n+1)*4);
  int* cur    = (int*)w;   w += alignup((size_t)n*4);
  int* csr    = (int*)w;   w += alignup((size_t)E*4);
  int* bsum   = (int*)w;   w += alignup(512*4);
  int* flag   = (int*)w;   w += alignup(64);
  unsigned short* wtH = (unsigned short*)w; w += alignup(512*64*2);
  unsigned short* wtL = (unsigned short*)w; w += alignup(512*64*2);

  const int nb_scan = (n + 1023) / 1024;

  k_zero<<<(n+255)/256, 256, 0, stream>>>(cnt, n);
  k_flag<<<1, 64, 0, stream>>>(ei, flag);
  k_wprep<<<128, 256, 0, stream>>>(W1, wtH, wtL);
  k_count<<<(E+255)/256, 256, 0, stream>>>(ei, flag, cnt, E);
  k_scan1<<<nb_scan, 256, 0, stream>>>(cnt, ro, bsum, n);
  k_scan2<<<1, 64, 0, stream>>>(bsum, nb_scan);
  k_scan3<<<(n+255)/256, 256, 0, stream>>>(ro, cur, bsum, n, E);
  k_fill<<<(E+255)/256, 256, 0, stream>>>(ei, flag, cur, csr, E);

  k_proj1<<<(n+127)/128, 256, 0, stream>>>(x, wtH, wtL, a1s, a1d, h1, al1s_, al1d_, n);
  k_agg1<<<(n+3)/4, 256, 0, stream>>>(ro, csr, al1s_, al1d_, h1, h1b, n);
  k_proj2<<<(n+15)/16, 256, 0, stream>>>(h1b, W2, a2s, a2d, h2, al2s_, al2d_, n);
  k_agg2<<<(n+3)/4, 256, 0, stream>>>(ro, csr, al2s_, al2d_, h2, out, n);
}

// Round 4
// 693.967 us; speedup vs baseline: 1.8080x; 1.1707x over previous
//
#include <hip/hip_runtime.h>
#include <math.h>

#define NEG 0.2f

typedef __attribute__((ext_vector_type(8))) short bf16x8;
typedef __attribute__((ext_vector_type(4))) float f32x4;

static __device__ __forceinline__ float lrelu(float x){ return x > 0.f ? x : NEG*x; }

// round-to-nearest-even fp32 -> bf16 split: v ~= hi + lo (each bf16)
static __device__ __forceinline__ void bsplit(float v, unsigned int& hi, unsigned int& lo){
  unsigned int u = __float_as_uint(v);
  unsigned int hb = (u + 0x7fffu + ((u >> 16) & 1u)) & 0xffff0000u;
  float hf = __uint_as_float(hb);
  float l = v - hf;
  unsigned int ul = __float_as_uint(l);
  hi = hb >> 16;
  lo = (ul + 0x7fffu + ((ul >> 16) & 1u)) >> 16;
}

// ---------------- utility ----------------
__global__ void k_zero(int* __restrict__ p, int n){
  int i = blockIdx.x*blockDim.x + threadIdx.x;
  if (i < n) p[i] = 0;
}

__global__ void k_flag(const int* __restrict__ u, int* __restrict__ flag){
  if (threadIdx.x == 0 && blockIdx.x == 0) {
    int z = 1;
    for (int e = 0; e < 64; ++e) if (u[2*e+1] != 0) { z = 0; break; }
    *flag = z;
  }
}

// ---------------- CSR build ----------------
__global__ void k_count(const int* __restrict__ u, const int* __restrict__ flag,
                        int* __restrict__ cnt, int E){
  int e = blockIdx.x*blockDim.x + threadIdx.x;
  if (e >= E) return;
  int dst = (*flag) ? u[2*(E+e)] : u[E+e];
  atomicAdd(&cnt[dst], 1);
}

__global__ __launch_bounds__(256) void k_scan1(const int* __restrict__ cnt,
    int* __restrict__ ro, int* __restrict__ bsum, int n){
  int t = threadIdx.x;
  int base = blockIdx.x*1024 + t*4;
  int v0 = (base+0 < n) ? cnt[base+0] : 0;
  int v1 = (base+1 < n) ? cnt[base+1] : 0;
  int v2 = (base+2 < n) ? cnt[base+2] : 0;
  int v3 = (base+3 < n) ? cnt[base+3] : 0;
  int s = v0+v1+v2+v3;
  int lane = t & 63, w = t >> 6;
  int inc = s;
  for (int off = 1; off < 64; off <<= 1) {
    int tm = __shfl_up(inc, off);
    if (lane >= off) inc += tm;
  }
  __shared__ int wsum[4];
  if (lane == 63) wsum[w] = inc;
  __syncthreads();
  int wpre = 0;
  for (int k = 0; k < 4; ++k) if (k < w) wpre += wsum[k];
  int run = wpre + inc - s;
  if (base+0 < n) ro[base+0] = run; run += v0;
  if (base+1 < n) ro[base+1] = run; run += v1;
  if (base+2 < n) ro[base+2] = run; run += v2;
  if (base+3 < n) ro[base+3] = run; run += v3;
  if (t == 255) bsum[blockIdx.x] = run;
}

__global__ void k_scan2(int* __restrict__ bsum, int nb){
  int lane = threadIdx.x;
  int carry = 0;
  for (int b = 0; b < nb; b += 64) {
    int i = b + lane;
    int v = (i < nb) ? bsum[i] : 0;
    int inc = v;
    for (int off = 1; off < 64; off <<= 1) {
      int t = __shfl_up(inc, off);
      if (lane >= off) inc += t;
    }
    if (i < nb) bsum[i] = carry + inc - v;
    carry += __shfl(inc, 63);
  }
}

__global__ void k_scan3(int* __restrict__ ro, int* __restrict__ cur,
                        const int* __restrict__ bsum, int n, int E){
  int i = blockIdx.x*blockDim.x + threadIdx.x;
  if (i < n) {
    int v = ro[i] + bsum[i >> 10];
    ro[i] = v; cur[i] = v;
  }
  if (i == 0) ro[n] = E;
}

// XCD-partitioned CSR fill: block b (assumed XCD b%8) scatters only edges whose
// dst lies in range [b%8 * n/8, ...). Its 1.6MB csr window stays L2-resident so
// lines fill completely before writeback (kills the 15x write amplification).
// Correct for ANY block->XCD mapping; the %8 match is perf-only.
__global__ __launch_bounds__(256) void k_fill(const int* __restrict__ u,
    const int* __restrict__ flag, int* __restrict__ cur, int* __restrict__ csr,
    int E, int n){
  const int xcd = blockIdx.x & 7;
  const int sub = blockIdx.x >> 3;
  const int nsub = gridDim.x >> 3;
  const int lo = (int)(((long long)xcd * n) >> 3);
  const int hi = (int)(((long long)(xcd + 1) * n) >> 3);
  const long long e0 = ((long long)sub * E) / nsub;
  const long long e1 = ((long long)(sub + 1) * E) / nsub;
  const bool f = (*flag) != 0;
  for (long long e = e0 + threadIdx.x; e < e1; e += 256) {
    int dst = f ? u[2*(E + e)] : u[E + e];
    if (dst >= lo && dst < hi) {
      int src = f ? u[2*e] : u[e];
      int p = atomicAdd(&cur[dst], 1);
      csr[p] = src;
    }
  }
}

// ---------------- W1 prep: transpose + bf16 split -> wtH/wtL [64][512] ----------------
__global__ void k_wprep(const float* __restrict__ W1, unsigned short* __restrict__ wtH,
                        unsigned short* __restrict__ wtL){
  int i = blockIdx.x*256 + threadIdx.x;   // over 512*64
  if (i >= 512*64) return;
  int k = i >> 6, c = i & 63;
  unsigned int hi, lo;
  bsplit(W1[i], hi, lo);
  wtH[c*512 + k] = (unsigned short)hi;
  wtL[c*512 + k] = (unsigned short)lo;
}

// ---------------- layer 1 projection: h1 = x @ W1 via split-bf16 MFMA ----------------
__global__ __launch_bounds__(256, 3) void k_proj1(const float* __restrict__ x,
    const unsigned short* __restrict__ wtH, const unsigned short* __restrict__ wtL,
    const float* __restrict__ a1s_g, const float* __restrict__ a1d_g,
    float* __restrict__ h1, float* __restrict__ al1s, float* __restrict__ al1d, int n){
  __shared__ unsigned short lds[24576];   // 48KB
  char* const ldsb = (char*)lds;          // xh@0 xl@16384 wh@32768 wl@40960
  const int tid = threadIdx.x;
  const int lane = tid & 63;
  const int w = tid >> 6;
  const int l16 = lane & 15;
  const int lhi = lane >> 4;
  const int n0 = blockIdx.x * 128;

  float as_c[4], ad_c[4];
  #pragma unroll
  for (int f = 0; f < 4; ++f) { as_c[f] = a1s_g[16*f + l16]; ad_c[f] = a1d_g[16*f + l16]; }

  f32x4 acc[2][4];
  #pragma unroll
  for (int m = 0; m < 2; ++m)
    #pragma unroll
    for (int f = 0; f < 4; ++f) acc[m][f] = (f32x4){0.f,0.f,0.f,0.f};

  for (int k0 = 0; k0 < 512; k0 += 64) {
    #pragma unroll
    for (int i = 0; i < 8; ++i) {
      int f4 = tid + i*256;         // 0..2047
      int row = f4 >> 4;            // 16 float4 per 64-float row
      int k4 = f4 & 15;
      int node = n0 + row; if (node >= n) node = n - 1;
      float4 v = *(const float4*)&x[(size_t)node*512 + k0 + k4*4];
      unsigned int h0,h1_,h2,h3,l0,l1,l2,l3;
      bsplit(v.x, h0, l0); bsplit(v.y, h1_, l1);
      bsplit(v.z, h2, l2); bsplit(v.w, h3, l3);
      uint2 hp = make_uint2(h0 | (h1_<<16), h2 | (h3<<16));
      uint2 lp = make_uint2(l0 | (l1<<16),  l2 | (l3<<16));
      int byteoff = (row*128 + k4*8) ^ ((row & 7) << 4);
      *(uint2*)(ldsb + byteoff)         = hp;
      *(uint2*)(ldsb + 16384 + byteoff) = lp;
    }
    #pragma unroll
    for (int i = 0; i < 2; ++i) {
      int f8 = tid + i*256;         // 0..511
      int c = f8 >> 3;
      int kb = f8 & 7;              // 8 bf16 per b128
      uint4 hv = *(const uint4*)&wtH[c*512 + k0 + kb*8];
      uint4 lv = *(const uint4*)&wtL[c*512 + k0 + kb*8];
      int byteoff = (c*128 + kb*16) ^ ((c & 7) << 4);
      *(uint4*)(ldsb + 32768 + byteoff) = hv;
      *(uint4*)(ldsb + 40960 + byteoff) = lv;
    }
    __syncthreads();

    #pragma unroll
    for (int kk = 0; kk < 64; kk += 32) {
      bf16x8 ah[2], al_[2], bh[4], bl[4];
      #pragma unroll
      for (int m = 0; m < 2; ++m) {
        int row = 32*w + 16*m + l16;
        int byteoff = (row*128 + (kk + 8*lhi)*2) ^ ((row & 7) << 4);
        ah[m]  = *(const bf16x8*)(ldsb + byteoff);
        al_[m] = *(const bf16x8*)(ldsb + 16384 + byteoff);
      }
      #pragma unroll
      for (int f = 0; f < 4; ++f) {
        int c = 16*f + l16;
        int byteoff = (c*128 + (kk + 8*lhi)*2) ^ ((c & 7) << 4);
        bh[f] = *(const bf16x8*)(ldsb + 32768 + byteoff);
        bl[f] = *(const bf16x8*)(ldsb + 40960 + byteoff);
      }
      #pragma unroll
      for (int m = 0; m < 2; ++m)
        #pragma unroll
        for (int f = 0; f < 4; ++f) {
          acc[m][f] = __builtin_amdgcn_mfma_f32_16x16x32_bf16(ah[m],  bh[f], acc[m][f], 0, 0, 0);
          acc[m][f] = __builtin_amdgcn_mfma_f32_16x16x32_bf16(ah[m],  bl[f], acc[m][f], 0, 0, 0);
          acc[m][f] = __builtin_amdgcn_mfma_f32_16x16x32_bf16(al_[m], bh[f], acc[m][f], 0, 0, 0);
        }
    }
    __syncthreads();
  }

  #pragma unroll
  for (int m = 0; m < 2; ++m) {
    #pragma unroll
    for (int r = 0; r < 4; ++r) {
      int node = n0 + 32*w + 16*m + 4*lhi + r;
      bool ok = (node < n);
      #pragma unroll
      for (int f = 0; f < 4; ++f) {
        float v = acc[m][f][r];
        if (ok) h1[(size_t)node*64 + 16*f + l16] = v;
        float vs = v * as_c[f], vd = v * ad_c[f];
        vs += __shfl_xor(vs, 1); vs += __shfl_xor(vs, 2); vs += __shfl_xor(vs, 4);
        vd += __shfl_xor(vd, 1); vd += __shfl_xor(vd, 2); vd += __shfl_xor(vd, 4);
        if (ok && (l16 & 7) == 0) {
          int head = 2*f + (l16 >> 3);
          al1s[node*8 + head] = vs;
          al1d[node*8 + head] = vd;
        }
      }
    }
  }
}

// ---------------- layer 1 aggregation + ELU (software-pipelined) ----------------
__global__ __launch_bounds__(256) void k_agg1(const int* __restrict__ ro,
    const int* __restrict__ csr, const float* __restrict__ al1s,
    const float* __restrict__ al1d, const float* __restrict__ h1,
    float* __restrict__ h1b, int n){
  int wid = blockIdx.x*4 + (threadIdx.x >> 6);
  if (wid >= n) return;
  int node = __builtin_amdgcn_readfirstlane(wid);
  int lane = threadIdx.x & 63;
  int h = lane >> 3;
  int beg = ro[node], end = ro[node+1];
  int m = end - beg;
  float ald = al1d[node*8 + h];
  float s = 0.f, acc = 0.f;
  int sA = (m > 0) ? csr[beg] : 0;
  int sB = (m > 1) ? csr[beg+1] : 0;
  float alA = al1s[sA*8 + h];
  float hvA = h1[(size_t)sA*64 + lane];
  for (int i = 0; i < m; ++i) {
    int sC = (i + 2 < m) ? csr[beg + i + 2] : 0;
    float alB = al1s[sB*8 + h];
    float hvB = h1[(size_t)sB*64 + lane];
    float e = alA + ald;
    e = e > 0.f ? e : NEG*e;
    float ex = __expf(e);
    s += ex;
    acc = fmaf(hvA, ex, acc);
    alA = alB; hvA = hvB; sB = sC;
  }
  float v = acc / (s + 1e-16f);
  v = v > 0.f ? v : expm1f(v);   // ELU
  h1b[(size_t)node*64 + lane] = v;
}

// ---------------- layer 2 projection ----------------
__global__ __launch_bounds__(256) void k_proj2(const float* __restrict__ h1b,
    const float* __restrict__ W2, const float* __restrict__ a2s_g, const float* __restrict__ a2d_g,
    float* __restrict__ h2, float* __restrict__ al2s, float* __restrict__ al2d, int n){
  __shared__ float w[64*16];
  __shared__ float a2sv[16], a2dv[16];
  for (int i = threadIdx.x; i < 1024; i += 256) w[i] = W2[i];
  if (threadIdx.x < 16) { a2sv[threadIdx.x] = a2s_g[threadIdx.x]; a2dv[threadIdx.x] = a2d_g[threadIdx.x]; }
  __syncthreads();
  int c = threadIdx.x & 15;
  int nid = blockIdx.x*16 + (threadIdx.x >> 4);
  if (nid >= n) return;
  const float* row = h1b + (size_t)nid*64;
  float acc = 0.f;
  #pragma unroll
  for (int k0 = 0; k0 < 64; k0 += 4) {
    float4 r = *(const float4*)(row + k0);
    acc = fmaf(r.x, w[(k0+0)*16 + c], acc);
    acc = fmaf(r.y, w[(k0+1)*16 + c], acc);
    acc = fmaf(r.z, w[(k0+2)*16 + c], acc);
    acc = fmaf(r.w, w[(k0+3)*16 + c], acc);
  }
  h2[(size_t)nid*16 + c] = acc;
  float vs = acc * a2sv[c], vd = acc * a2dv[c];
  vs += __shfl_xor(vs, 1); vs += __shfl_xor(vs, 2); vs += __shfl_xor(vs, 4); vs += __shfl_xor(vs, 8);
  vd += __shfl_xor(vd, 1); vd += __shfl_xor(vd, 2); vd += __shfl_xor(vd, 4); vd += __shfl_xor(vd, 8);
  if (c == 0) { al2s[nid] = vs; al2d[nid] = vd; }
}

// ---------------- layer 2 aggregation + log_softmax ----------------
__global__ __launch_bounds__(256) void k_agg2(const int* __restrict__ ro,
    const int* __restrict__ csr, const float* __restrict__ al2s,
    const float* __restrict__ al2d, const float* __restrict__ h2,
    float* __restrict__ out, int n){
  int wid = blockIdx.x*4 + (threadIdx.x >> 6);
  if (wid >= n) return;
  int node = __builtin_amdgcn_readfirstlane(wid);
  int lane = threadIdx.x & 63;
  int j = lane >> 4, c = lane & 15;
  int beg = ro[node], end = ro[node+1];
  float ald = al2d[node];
  float sp = 0.f, acc = 0.f;
  for (int i = beg + j; i < end; i += 4) {
    int src = csr[i];
    float e = lrelu(al2s[src] + ald);
    float ex = __expf(e);
    sp += ex;
    acc = fmaf(ex, h2[(size_t)src*16 + c], acc);
  }
  sp  += __shfl_xor(sp, 16);  sp  += __shfl_xor(sp, 32);
  acc += __shfl_xor(acc, 16); acc += __shfl_xor(acc, 32);
  float v = acc / (sp + 1e-16f);
  float mx = v;
  mx = fmaxf(mx, __shfl_xor(mx, 1)); mx = fmaxf(mx, __shfl_xor(mx, 2));
  mx = fmaxf(mx, __shfl_xor(mx, 4)); mx = fmaxf(mx, __shfl_xor(mx, 8));
  float l = v - mx;
  float se = __expf(l);
  se += __shfl_xor(se, 1); se += __shfl_xor(se, 2);
  se += __shfl_xor(se, 4); se += __shfl_xor(se, 8);
  float res = l - logf(se);
  if (j == 0) out[(size_t)node*16 + c] = res;
}

// ---------------- host ----------------
static inline size_t alignup(size_t x){ return (x + 255) & ~(size_t)255; }

extern "C" void kernel_launch(void* const* d_in, const int* in_sizes, int n_in,
                              void* d_out, int out_size, void* d_ws, size_t ws_size,
                              hipStream_t stream){
  const float* x   = (const float*)d_in[0];
  const int*   ei  = (const int*)  d_in[1];
  const float* W1  = (const float*)d_in[2];
  const float* a1s = (const float*)d_in[3];
  const float* a1d = (const float*)d_in[4];
  const float* W2  = (const float*)d_in[5];
  const float* a2s = (const float*)d_in[6];
  const float* a2d = (const float*)d_in[7];
  float* out = (float*)d_out;

  const int n = in_sizes[0] / 512;   // 100000
  const int E = in_sizes[1] / 2;     // 3200000

  char* w = (char*)d_ws;
  float* h1   = (float*)w; w += alignup((size_t)n*64*4);
  float* h1b  = (float*)w; w += alignup((size_t)n*64*4);
  float* al1s_ = (float*)w; w += alignup((size_t)n*8*4);
  float* al1d_ = (float*)w; w += alignup((size_t)n*8*4);
  float* h2   = (float*)w; w += alignup((size_t)n*16*4);
  float* al2s_ = (float*)w; w += alignup((size_t)n*4);
  float* al2d_ = (float*)w; w += alignup((size_t)n*4);
  int* cnt    = (int*)w;   w += alignup((size_t)n*4);
  int* ro     = (int*)w;   w += alignup((size_t)(n+1)*4);
  int* cur    = (int*)w;   w += alignup((size_t)n*4);
  int* csr    = (int*)w;   w += alignup((size_t)E*4);
  int* bsum   = (int*)w;   w += alignup(512*4);
  int* flag   = (int*)w;   w += alignup(64);
  unsigned short* wtH = (unsigned short*)w; w += alignup(512*64*2);
  unsigned short* wtL = (unsigned short*)w; w += alignup(512*64*2);

  const int nb_scan = (n + 1023) / 1024;

  k_zero<<<(n+255)/256, 256, 0, stream>>>(cnt, n);
  k_flag<<<1, 64, 0, stream>>>(ei, flag);
  k_wprep<<<128, 256, 0, stream>>>(W1, wtH, wtL);
  k_count<<<(E+255)/256, 256, 0, stream>>>(ei, flag, cnt, E);
  k_scan1<<<nb_scan, 256, 0, stream>>>(cnt, ro, bsum, n);
  k_scan2<<<1, 64, 0, stream>>>(bsum, nb_scan);
  k_scan3<<<(n+255)/256, 256, 0, stream>>>(ro, cur, bsum, n, E);
  k_fill<<<2048, 256, 0, stream>>>(ei, flag, cur, csr, E, n);

  k_proj1<<<(n+127)/128, 256, 0, stream>>>(x, wtH, wtL, a1s, a1d, h1, al1s_, al1d_, n);
  k_agg1<<<(n+3)/4, 256, 0, stream>>>(ro, csr, al1s_, al1d_, h1, h1b, n);
  k_proj2<<<(n+15)/16, 256, 0, stream>>>(h1b, W2, a2s, a2d, h2, al2s_, al2d_, n);
  k_agg2<<<(n+3)/4, 256, 0, stream>>>(ro, csr, al2s_, al2d_, h2, out, n);
}

// Round 5
// 587.533 us; speedup vs baseline: 2.1355x; 1.1812x over previous
//
#include <hip/hip_runtime.h>
#include <math.h>

#define NEG 0.2f

typedef __attribute__((ext_vector_type(8))) short bf16x8;
typedef __attribute__((ext_vector_type(4))) float f32x4;

static __device__ __forceinline__ float lrelu(float x){ return x > 0.f ? x : NEG*x; }

// round-to-nearest-even fp32 -> bf16 split: v ~= hi + lo (each bf16)
static __device__ __forceinline__ void bsplit(float v, unsigned int& hi, unsigned int& lo){
  unsigned int u = __float_as_uint(v);
  unsigned int hb = (u + 0x7fffu + ((u >> 16) & 1u)) & 0xffff0000u;
  float hf = __uint_as_float(hb);
  float l = v - hf;
  unsigned int ul = __float_as_uint(l);
  hi = hb >> 16;
  lo = (ul + 0x7fffu + ((ul >> 16) & 1u)) >> 16;
}

static __device__ __forceinline__ float bf2f(unsigned short u){
  return __uint_as_float(((unsigned int)u) << 16);
}
static __device__ __forceinline__ unsigned short f2bf(float v){
  unsigned int u = __float_as_uint(v);
  return (unsigned short)((u + 0x7fffu + ((u >> 16) & 1u)) >> 16);
}

// ---------------- utility ----------------
__global__ void k_zero(int* __restrict__ p, int n){
  int i = blockIdx.x*blockDim.x + threadIdx.x;
  if (i < n) p[i] = 0;
}

__global__ void k_flag(const int* __restrict__ u, int* __restrict__ flag){
  if (threadIdx.x == 0 && blockIdx.x == 0) {
    int z = 1;
    for (int e = 0; e < 64; ++e) if (u[2*e+1] != 0) { z = 0; break; }
    *flag = z;
  }
}

// ---------------- CSR build ----------------
__global__ void k_count(const int* __restrict__ u, const int* __restrict__ flag,
                        int* __restrict__ cnt, int E){
  int e = blockIdx.x*blockDim.x + threadIdx.x;
  if (e >= E) return;
  int dst = (*flag) ? u[2*(E+e)] : u[E+e];
  atomicAdd(&cnt[dst], 1);
}

__global__ __launch_bounds__(256) void k_scan1(const int* __restrict__ cnt,
    int* __restrict__ ro, int* __restrict__ bsum, int n){
  int t = threadIdx.x;
  int base = blockIdx.x*1024 + t*4;
  int v0 = (base+0 < n) ? cnt[base+0] : 0;
  int v1 = (base+1 < n) ? cnt[base+1] : 0;
  int v2 = (base+2 < n) ? cnt[base+2] : 0;
  int v3 = (base+3 < n) ? cnt[base+3] : 0;
  int s = v0+v1+v2+v3;
  int lane = t & 63, w = t >> 6;
  int inc = s;
  for (int off = 1; off < 64; off <<= 1) {
    int tm = __shfl_up(inc, off);
    if (lane >= off) inc += tm;
  }
  __shared__ int wsum[4];
  if (lane == 63) wsum[w] = inc;
  __syncthreads();
  int wpre = 0;
  for (int k = 0; k < 4; ++k) if (k < w) wpre += wsum[k];
  int run = wpre + inc - s;
  if (base+0 < n) ro[base+0] = run; run += v0;
  if (base+1 < n) ro[base+1] = run; run += v1;
  if (base+2 < n) ro[base+2] = run; run += v2;
  if (base+3 < n) ro[base+3] = run; run += v3;
  if (t == 255) bsum[blockIdx.x] = run;
}

__global__ void k_scan2(int* __restrict__ bsum, int nb){
  int lane = threadIdx.x;
  int carry = 0;
  for (int b = 0; b < nb; b += 64) {
    int i = b + lane;
    int v = (i < nb) ? bsum[i] : 0;
    int inc = v;
    for (int off = 1; off < 64; off <<= 1) {
      int t = __shfl_up(inc, off);
      if (lane >= off) inc += t;
    }
    if (i < nb) bsum[i] = carry + inc - v;
    carry += __shfl(inc, 63);
  }
}

__global__ void k_scan3(int* __restrict__ ro, int* __restrict__ cur,
                        const int* __restrict__ bsum, int n, int E){
  int i = blockIdx.x*blockDim.x + threadIdx.x;
  if (i < n) {
    int v = ro[i] + bsum[i >> 10];
    ro[i] = v; cur[i] = v;
  }
  if (i == 0) ro[n] = E;
}

// XCD-partitioned CSR fill (see round-3 note): csr window per XCD stays L2-resident.
__global__ __launch_bounds__(256) void k_fill(const int* __restrict__ u,
    const int* __restrict__ flag, int* __restrict__ cur, int* __restrict__ csr,
    int E, int n){
  const int xcd = blockIdx.x & 7;
  const int sub = blockIdx.x >> 3;
  const int nsub = gridDim.x >> 3;
  const int lo = (int)(((long long)xcd * n) >> 3);
  const int hi = (int)(((long long)(xcd + 1) * n) >> 3);
  const long long e0 = ((long long)sub * E) / nsub;
  const long long e1 = ((long long)(sub + 1) * E) / nsub;
  const bool f = (*flag) != 0;
  for (long long e = e0 + threadIdx.x; e < e1; e += 256) {
    int dst = f ? u[2*(E + e)] : u[E + e];
    if (dst >= lo && dst < hi) {
      int src = f ? u[2*e] : u[e];
      int p = atomicAdd(&cur[dst], 1);
      csr[p] = src;
    }
  }
}

// ---------------- W1 prep: transpose + bf16 split -> wtH/wtL [64][512] ----------------
__global__ void k_wprep(const float* __restrict__ W1, unsigned short* __restrict__ wtH,
                        unsigned short* __restrict__ wtL){
  int i = blockIdx.x*256 + threadIdx.x;   // over 512*64
  if (i >= 512*64) return;
  int k = i >> 6, c = i & 63;
  unsigned int hi, lo;
  bsplit(W1[i], hi, lo);
  wtH[c*512 + k] = (unsigned short)hi;
  wtL[c*512 + k] = (unsigned short)lo;
}

// ---------------- layer 1 projection: h1 = x @ W1 via split-bf16 MFMA ----------------
// h1 is written as bf16 (gather payload for agg1); attention logits stay fp32.
__global__ __launch_bounds__(256, 3) void k_proj1(const float* __restrict__ x,
    const unsigned short* __restrict__ wtH, const unsigned short* __restrict__ wtL,
    const float* __restrict__ a1s_g, const float* __restrict__ a1d_g,
    unsigned short* __restrict__ h1bf, float* __restrict__ al1s, float* __restrict__ al1d, int n){
  __shared__ unsigned short lds[24576];   // 48KB
  char* const ldsb = (char*)lds;          // xh@0 xl@16384 wh@32768 wl@40960
  const int tid = threadIdx.x;
  const int lane = tid & 63;
  const int w = tid >> 6;
  const int l16 = lane & 15;
  const int lhi = lane >> 4;
  const int n0 = blockIdx.x * 128;

  float as_c[4], ad_c[4];
  #pragma unroll
  for (int f = 0; f < 4; ++f) { as_c[f] = a1s_g[16*f + l16]; ad_c[f] = a1d_g[16*f + l16]; }

  f32x4 acc[2][4];
  #pragma unroll
  for (int m = 0; m < 2; ++m)
    #pragma unroll
    for (int f = 0; f < 4; ++f) acc[m][f] = (f32x4){0.f,0.f,0.f,0.f};

  for (int k0 = 0; k0 < 512; k0 += 64) {
    #pragma unroll
    for (int i = 0; i < 8; ++i) {
      int f4 = tid + i*256;         // 0..2047
      int row = f4 >> 4;            // 16 float4 per 64-float row
      int k4 = f4 & 15;
      int node = n0 + row; if (node >= n) node = n - 1;
      float4 v = *(const float4*)&x[(size_t)node*512 + k0 + k4*4];
      unsigned int h0,h1_,h2,h3,l0,l1,l2,l3;
      bsplit(v.x, h0, l0); bsplit(v.y, h1_, l1);
      bsplit(v.z, h2, l2); bsplit(v.w, h3, l3);
      uint2 hp = make_uint2(h0 | (h1_<<16), h2 | (h3<<16));
      uint2 lp = make_uint2(l0 | (l1<<16),  l2 | (l3<<16));
      int byteoff = (row*128 + k4*8) ^ ((row & 7) << 4);
      *(uint2*)(ldsb + byteoff)         = hp;
      *(uint2*)(ldsb + 16384 + byteoff) = lp;
    }
    #pragma unroll
    for (int i = 0; i < 2; ++i) {
      int f8 = tid + i*256;         // 0..511
      int c = f8 >> 3;
      int kb = f8 & 7;              // 8 bf16 per b128
      uint4 hv = *(const uint4*)&wtH[c*512 + k0 + kb*8];
      uint4 lv = *(const uint4*)&wtL[c*512 + k0 + kb*8];
      int byteoff = (c*128 + kb*16) ^ ((c & 7) << 4);
      *(uint4*)(ldsb + 32768 + byteoff) = hv;
      *(uint4*)(ldsb + 40960 + byteoff) = lv;
    }
    __syncthreads();

    #pragma unroll
    for (int kk = 0; kk < 64; kk += 32) {
      bf16x8 ah[2], al_[2], bh[4], bl[4];
      #pragma unroll
      for (int m = 0; m < 2; ++m) {
        int row = 32*w + 16*m + l16;
        int byteoff = (row*128 + (kk + 8*lhi)*2) ^ ((row & 7) << 4);
        ah[m]  = *(const bf16x8*)(ldsb + byteoff);
        al_[m] = *(const bf16x8*)(ldsb + 16384 + byteoff);
      }
      #pragma unroll
      for (int f = 0; f < 4; ++f) {
        int c = 16*f + l16;
        int byteoff = (c*128 + (kk + 8*lhi)*2) ^ ((c & 7) << 4);
        bh[f] = *(const bf16x8*)(ldsb + 32768 + byteoff);
        bl[f] = *(const bf16x8*)(ldsb + 40960 + byteoff);
      }
      #pragma unroll
      for (int m = 0; m < 2; ++m)
        #pragma unroll
        for (int f = 0; f < 4; ++f) {
          acc[m][f] = __builtin_amdgcn_mfma_f32_16x16x32_bf16(ah[m],  bh[f], acc[m][f], 0, 0, 0);
          acc[m][f] = __builtin_amdgcn_mfma_f32_16x16x32_bf16(ah[m],  bl[f], acc[m][f], 0, 0, 0);
          acc[m][f] = __builtin_amdgcn_mfma_f32_16x16x32_bf16(al_[m], bh[f], acc[m][f], 0, 0, 0);
        }
    }
    __syncthreads();
  }

  #pragma unroll
  for (int m = 0; m < 2; ++m) {
    #pragma unroll
    for (int r = 0; r < 4; ++r) {
      int node = n0 + 32*w + 16*m + 4*lhi + r;
      bool ok = (node < n);
      #pragma unroll
      for (int f = 0; f < 4; ++f) {
        float v = acc[m][f][r];
        if (ok) h1bf[(size_t)node*64 + 16*f + l16] = f2bf(v);
        float vs = v * as_c[f], vd = v * ad_c[f];
        vs += __shfl_xor(vs, 1); vs += __shfl_xor(vs, 2); vs += __shfl_xor(vs, 4);
        vd += __shfl_xor(vd, 1); vd += __shfl_xor(vd, 2); vd += __shfl_xor(vd, 4);
        if (ok && (l16 & 7) == 0) {
          int head = 2*f + (l16 >> 3);
          al1s[node*8 + head] = vs;
          al1d[node*8 + head] = vd;
        }
      }
    }
  }
}

// ---------------- layer 1 aggregation + ELU (4-deep pipelined, bf16 gather) ----------------
__global__ __launch_bounds__(256) void k_agg1(const int* __restrict__ ro,
    const int* __restrict__ csr, const float* __restrict__ al1s,
    const float* __restrict__ al1d, const unsigned short* __restrict__ h1bf,
    float* __restrict__ h1b, int n){
  int wid = blockIdx.x*4 + (threadIdx.x >> 6);
  if (wid >= n) return;
  int node = __builtin_amdgcn_readfirstlane(wid);
  int lane = threadIdx.x & 63;
  int h = lane >> 3;
  int beg = ro[node], end = ro[node+1];
  float ald = al1d[node*8 + h];
  float s = 0.f, acc = 0.f;
  if (beg < end) {
    int   srcb[4];
    float alb[4], hvb[4];
    #pragma unroll
    for (int j = 0; j < 4; ++j) {
      int idx = beg + j;
      srcb[j] = csr[idx < end ? idx : beg];
    }
    #pragma unroll
    for (int j = 0; j < 4; ++j) {
      alb[j] = al1s[srcb[j]*8 + h];
      hvb[j] = bf2f(h1bf[(size_t)srcb[j]*64 + lane]);
    }
    for (int t = beg; t < end; t += 4) {
      int   nsrc[4];
      float nal[4], nhv[4];
      #pragma unroll
      for (int j = 0; j < 4; ++j) {
        int idx = t + 4 + j;
        nsrc[j] = csr[idx < end ? idx : beg];
      }
      #pragma unroll
      for (int j = 0; j < 4; ++j) {
        nal[j] = al1s[nsrc[j]*8 + h];
        nhv[j] = bf2f(h1bf[(size_t)nsrc[j]*64 + lane]);
      }
      #pragma unroll
      for (int j = 0; j < 4; ++j) {
        float e = alb[j] + ald;
        e = e > 0.f ? e : NEG*e;
        float ex = (t + j < end) ? __expf(e) : 0.f;
        s += ex;
        acc = fmaf(hvb[j], ex, acc);
      }
      #pragma unroll
      for (int j = 0; j < 4; ++j) { srcb[j] = nsrc[j]; alb[j] = nal[j]; hvb[j] = nhv[j]; }
    }
  }
  float v = acc / (s + 1e-16f);
  v = v > 0.f ? v : expm1f(v);   // ELU
  h1b[(size_t)node*64 + lane] = v;
}

// ---------------- layer 2 projection (h2 stored bf16 for agg2 gather) ----------------
__global__ __launch_bounds__(256) void k_proj2(const float* __restrict__ h1b,
    const float* __restrict__ W2, const float* __restrict__ a2s_g, const float* __restrict__ a2d_g,
    unsigned short* __restrict__ h2bf, float* __restrict__ al2s, float* __restrict__ al2d, int n){
  __shared__ float w[64*16];
  __shared__ float a2sv[16], a2dv[16];
  for (int i = threadIdx.x; i < 1024; i += 256) w[i] = W2[i];
  if (threadIdx.x < 16) { a2sv[threadIdx.x] = a2s_g[threadIdx.x]; a2dv[threadIdx.x] = a2d_g[threadIdx.x]; }
  __syncthreads();
  int c = threadIdx.x & 15;
  int nid = blockIdx.x*16 + (threadIdx.x >> 4);
  if (nid >= n) return;
  const float* row = h1b + (size_t)nid*64;
  float acc = 0.f;
  #pragma unroll
  for (int k0 = 0; k0 < 64; k0 += 4) {
    float4 r = *(const float4*)(row + k0);
    acc = fmaf(r.x, w[(k0+0)*16 + c], acc);
    acc = fmaf(r.y, w[(k0+1)*16 + c], acc);
    acc = fmaf(r.z, w[(k0+2)*16 + c], acc);
    acc = fmaf(r.w, w[(k0+3)*16 + c], acc);
  }
  h2bf[(size_t)nid*16 + c] = f2bf(acc);
  float vs = acc * a2sv[c], vd = acc * a2dv[c];
  vs += __shfl_xor(vs, 1); vs += __shfl_xor(vs, 2); vs += __shfl_xor(vs, 4); vs += __shfl_xor(vs, 8);
  vd += __shfl_xor(vd, 1); vd += __shfl_xor(vd, 2); vd += __shfl_xor(vd, 4); vd += __shfl_xor(vd, 8);
  if (c == 0) { al2s[nid] = vs; al2d[nid] = vd; }
}

// ---------------- layer 2 aggregation + log_softmax (2-deep pipelined) ----------------
__global__ __launch_bounds__(256) void k_agg2(const int* __restrict__ ro,
    const int* __restrict__ csr, const float* __restrict__ al2s,
    const float* __restrict__ al2d, const unsigned short* __restrict__ h2bf,
    float* __restrict__ out, int n){
  int wid = blockIdx.x*4 + (threadIdx.x >> 6);
  if (wid >= n) return;
  int node = __builtin_amdgcn_readfirstlane(wid);
  int lane = threadIdx.x & 63;
  int j = lane >> 4, c = lane & 15;
  int beg = ro[node], end = ro[node+1];
  float ald = al2d[node];
  float sp = 0.f, acc = 0.f;
  if (beg < end) {
    int i = beg + j;
    int sA = csr[i < end ? i : beg];
    float aA = al2s[sA];
    float hA = bf2f(h2bf[(size_t)sA*16 + c]);
    for (; i < end; i += 4) {
      int i2 = i + 4;
      int sB = csr[i2 < end ? i2 : beg];
      float aB = al2s[sB];
      float hB = bf2f(h2bf[(size_t)sB*16 + c]);
      float e = lrelu(aA + ald);
      float ex = __expf(e);
      sp += ex;
      acc = fmaf(ex, hA, acc);
      sA = sB; aA = aB; hA = hB;
    }
  }
  sp  += __shfl_xor(sp, 16);  sp  += __shfl_xor(sp, 32);
  acc += __shfl_xor(acc, 16); acc += __shfl_xor(acc, 32);
  float v = acc / (sp + 1e-16f);
  float mx = v;
  mx = fmaxf(mx, __shfl_xor(mx, 1)); mx = fmaxf(mx, __shfl_xor(mx, 2));
  mx = fmaxf(mx, __shfl_xor(mx, 4)); mx = fmaxf(mx, __shfl_xor(mx, 8));
  float l = v - mx;
  float se = __expf(l);
  se += __shfl_xor(se, 1); se += __shfl_xor(se, 2);
  se += __shfl_xor(se, 4); se += __shfl_xor(se, 8);
  float res = l - logf(se);
  if (j == 0) out[(size_t)node*16 + c] = res;
}

// ---------------- host ----------------
static inline size_t alignup(size_t x){ return (x + 255) & ~(size_t)255; }

extern "C" void kernel_launch(void* const* d_in, const int* in_sizes, int n_in,
                              void* d_out, int out_size, void* d_ws, size_t ws_size,
                              hipStream_t stream){
  const float* x   = (const float*)d_in[0];
  const int*   ei  = (const int*)  d_in[1];
  const float* W1  = (const float*)d_in[2];
  const float* a1s = (const float*)d_in[3];
  const float* a1d = (const float*)d_in[4];
  const float* W2  = (const float*)d_in[5];
  const float* a2s = (const float*)d_in[6];
  const float* a2d = (const float*)d_in[7];
  float* out = (float*)d_out;

  const int n = in_sizes[0] / 512;   // 100000
  const int E = in_sizes[1] / 2;     // 3200000

  char* w = (char*)d_ws;
  unsigned short* h1bf = (unsigned short*)w; w += alignup((size_t)n*64*2);
  float* h1b  = (float*)w; w += alignup((size_t)n*64*4);
  float* al1s_ = (float*)w; w += alignup((size_t)n*8*4);
  float* al1d_ = (float*)w; w += alignup((size_t)n*8*4);
  unsigned short* h2bf = (unsigned short*)w; w += alignup((size_t)n*16*2);
  float* al2s_ = (float*)w; w += alignup((size_t)n*4);
  float* al2d_ = (float*)w; w += alignup((size_t)n*4);
  int* cnt    = (int*)w;   w += alignup((size_t)n*4);
  int* ro     = (int*)w;   w += alignup((size_t)(n+1)*4);
  int* cur    = (int*)w;   w += alignup((size_t)n*4);
  int* csr    = (int*)w;   w += alignup((size_t)E*4);
  int* bsum   = (int*)w;   w += alignup(512*4);
  int* flag   = (int*)w;   w += alignup(64);
  unsigned short* wtH = (unsigned short*)w; w += alignup(512*64*2);
  unsigned short* wtL = (unsigned short*)w; w += alignup(512*64*2);

  const int nb_scan = (n + 1023) / 1024;

  k_zero<<<(n+255)/256, 256, 0, stream>>>(cnt, n);
  k_flag<<<1, 64, 0, stream>>>(ei, flag);
  k_wprep<<<128, 256, 0, stream>>>(W1, wtH, wtL);
  k_count<<<(E+255)/256, 256, 0, stream>>>(ei, flag, cnt, E);
  k_scan1<<<nb_scan, 256, 0, stream>>>(cnt, ro, bsum, n);
  k_scan2<<<1, 64, 0, stream>>>(bsum, nb_scan);
  k_scan3<<<(n+255)/256, 256, 0, stream>>>(ro, cur, bsum, n, E);
  k_fill<<<2048, 256, 0, stream>>>(ei, flag, cur, csr, E, n);

  k_proj1<<<(n+127)/128, 256, 0, stream>>>(x, wtH, wtL, a1s, a1d, h1bf, al1s_, al1d_, n);
  k_agg1<<<(n+3)/4, 256, 0, stream>>>(ro, csr, al1s_, al1d_, h1bf, h1b, n);
  k_proj2<<<(n+15)/16, 256, 0, stream>>>(h1b, W2, a2s, a2d, h2bf, al2s_, al2d_, n);
  k_agg2<<<(n+3)/4, 256, 0, stream>>>(ro, csr, al2s_, al2d_, h2bf, out, n);
}

// Round 6
// 582.837 us; speedup vs baseline: 2.1528x; 1.0081x over previous
//
#include <hip/hip_runtime.h>
#include <math.h>

#define NEG 0.2f

typedef __attribute__((ext_vector_type(8))) short bf16x8;
typedef __attribute__((ext_vector_type(4))) float f32x4;

static __device__ __forceinline__ float lrelu(float x){ return x > 0.f ? x : NEG*x; }

// round-to-nearest-even fp32 -> bf16 split: v ~= hi + lo (each bf16)
static __device__ __forceinline__ void bsplit(float v, unsigned int& hi, unsigned int& lo){
  unsigned int u = __float_as_uint(v);
  unsigned int hb = (u + 0x7fffu + ((u >> 16) & 1u)) & 0xffff0000u;
  float hf = __uint_as_float(hb);
  float l = v - hf;
  unsigned int ul = __float_as_uint(l);
  hi = hb >> 16;
  lo = (ul + 0x7fffu + ((ul >> 16) & 1u)) >> 16;
}

static __device__ __forceinline__ float bf2f(unsigned short u){
  return __uint_as_float(((unsigned int)u) << 16);
}
static __device__ __forceinline__ unsigned short f2bf(float v){
  unsigned int u = __float_as_uint(v);
  return (unsigned short)((u + 0x7fffu + ((u >> 16) & 1u)) >> 16);
}

// split 8 consecutive floats (two float4) into hi/lo bf16x8 fragments
static __device__ __forceinline__ void split8(float4 v0, float4 v1, bf16x8& h, bf16x8& l){
  float vv[8] = {v0.x, v0.y, v0.z, v0.w, v1.x, v1.y, v1.z, v1.w};
  #pragma unroll
  for (int i = 0; i < 8; ++i) {
    unsigned int hi, lo;
    bsplit(vv[i], hi, lo);
    h[i] = (short)hi;
    l[i] = (short)lo;
  }
}

// ---------------- utility ----------------
__global__ void k_zero(int* __restrict__ p, int n){
  int i = blockIdx.x*blockDim.x + threadIdx.x;
  if (i < n) p[i] = 0;
}

__global__ void k_flag(const int* __restrict__ u, int* __restrict__ flag){
  if (threadIdx.x == 0 && blockIdx.x == 0) {
    int z = 1;
    for (int e = 0; e < 64; ++e) if (u[2*e+1] != 0) { z = 0; break; }
    *flag = z;
  }
}

// ---------------- CSR build ----------------
__global__ void k_count(const int* __restrict__ u, const int* __restrict__ flag,
                        int* __restrict__ cnt, int E){
  int e = blockIdx.x*blockDim.x + threadIdx.x;
  if (e >= E) return;
  int dst = (*flag) ? u[2*(E+e)] : u[E+e];
  atomicAdd(&cnt[dst], 1);
}

__global__ __launch_bounds__(256) void k_scan1(const int* __restrict__ cnt,
    int* __restrict__ ro, int* __restrict__ bsum, int n){
  int t = threadIdx.x;
  int base = blockIdx.x*1024 + t*4;
  int v0 = (base+0 < n) ? cnt[base+0] : 0;
  int v1 = (base+1 < n) ? cnt[base+1] : 0;
  int v2 = (base+2 < n) ? cnt[base+2] : 0;
  int v3 = (base+3 < n) ? cnt[base+3] : 0;
  int s = v0+v1+v2+v3;
  int lane = t & 63, w = t >> 6;
  int inc = s;
  for (int off = 1; off < 64; off <<= 1) {
    int tm = __shfl_up(inc, off);
    if (lane >= off) inc += tm;
  }
  __shared__ int wsum[4];
  if (lane == 63) wsum[w] = inc;
  __syncthreads();
  int wpre = 0;
  for (int k = 0; k < 4; ++k) if (k < w) wpre += wsum[k];
  int run = wpre + inc - s;
  if (base+0 < n) ro[base+0] = run; run += v0;
  if (base+1 < n) ro[base+1] = run; run += v1;
  if (base+2 < n) ro[base+2] = run; run += v2;
  if (base+3 < n) ro[base+3] = run; run += v3;
  if (t == 255) bsum[blockIdx.x] = run;
}

__global__ void k_scan2(int* __restrict__ bsum, int nb){
  int lane = threadIdx.x;
  int carry = 0;
  for (int b = 0; b < nb; b += 64) {
    int i = b + lane;
    int v = (i < nb) ? bsum[i] : 0;
    int inc = v;
    for (int off = 1; off < 64; off <<= 1) {
      int t = __shfl_up(inc, off);
      if (lane >= off) inc += t;
    }
    if (i < nb) bsum[i] = carry + inc - v;
    carry += __shfl(inc, 63);
  }
}

__global__ void k_scan3(int* __restrict__ ro, int* __restrict__ cur,
                        const int* __restrict__ bsum, int n, int E){
  int i = blockIdx.x*blockDim.x + threadIdx.x;
  if (i < n) {
    int v = ro[i] + bsum[i >> 10];
    ro[i] = v; cur[i] = v;
  }
  if (i == 0) ro[n] = E;
}

// XCD-partitioned CSR fill (see round-3 note): csr window per XCD stays L2-resident.
__global__ __launch_bounds__(256) void k_fill(const int* __restrict__ u,
    const int* __restrict__ flag, int* __restrict__ cur, int* __restrict__ csr,
    int E, int n){
  const int xcd = blockIdx.x & 7;
  const int sub = blockIdx.x >> 3;
  const int nsub = gridDim.x >> 3;
  const int lo = (int)(((long long)xcd * n) >> 3);
  const int hi = (int)(((long long)(xcd + 1) * n) >> 3);
  const long long e0 = ((long long)sub * E) / nsub;
  const long long e1 = ((long long)(sub + 1) * E) / nsub;
  const bool f = (*flag) != 0;
  for (long long e = e0 + threadIdx.x; e < e1; e += 256) {
    int dst = f ? u[2*(E + e)] : u[E + e];
    if (dst >= lo && dst < hi) {
      int src = f ? u[2*e] : u[e];
      int p = atomicAdd(&cur[dst], 1);
      csr[p] = src;
    }
  }
}

// ---------------- W1 prep: transpose + bf16 split -> wtH/wtL [64][512] ----------------
__global__ void k_wprep(const float* __restrict__ W1, unsigned short* __restrict__ wtH,
                        unsigned short* __restrict__ wtL){
  int i = blockIdx.x*256 + threadIdx.x;   // over 512*64
  if (i >= 512*64) return;
  int k = i >> 6, c = i & 63;
  unsigned int hi, lo;
  bsplit(W1[i], hi, lo);
  wtH[c*512 + k] = (unsigned short)hi;
  wtL[c*512 + k] = (unsigned short)lo;
}

// ---------------- layer 1 projection: h1 = x @ W1 via split-bf16 MFMA ----------------
// NO LDS, NO barriers: fragments loaded straight from global.
// A-fragment (row=l&15, k=8*(l>>4)+i) = 8 consecutive fp32 of one x row
//   -> two dwordx4; lanes {l16, lhi=0..3} cover 128B contiguous per row.
// B-fragment = 16B contiguous of pre-transposed wtH/wtL (128KB, L2-resident).
// Each wave owns 32 rows; waves fully independent -> compiler pipelines loads
// across K-iterations; occupancy VGPR-limited only.
__global__ __launch_bounds__(256, 3) void k_proj1(const float* __restrict__ x,
    const unsigned short* __restrict__ wtH, const unsigned short* __restrict__ wtL,
    const float* __restrict__ a1s_g, const float* __restrict__ a1d_g,
    unsigned short* __restrict__ h1bf, float* __restrict__ al1s, float* __restrict__ al1d, int n){
  const int tid = threadIdx.x;
  const int lane = tid & 63;
  const int w = tid >> 6;
  const int l16 = lane & 15;
  const int lhi = lane >> 4;                 // 0..3
  const int r0 = blockIdx.x*128 + w*32;      // this wave's 32 rows

  float as_c[4], ad_c[4];
  #pragma unroll
  for (int f = 0; f < 4; ++f) { as_c[f] = a1s_g[16*f + l16]; ad_c[f] = a1d_g[16*f + l16]; }

  f32x4 acc[2][4];
  #pragma unroll
  for (int m = 0; m < 2; ++m)
    #pragma unroll
    for (int f = 0; f < 4; ++f) acc[m][f] = (f32x4){0.f,0.f,0.f,0.f};

  int rowA = r0 + l16;        if (rowA >= n) rowA = n - 1;
  int rowB = r0 + 16 + l16;   if (rowB >= n) rowB = n - 1;
  const float* xA = x + (size_t)rowA*512 + 8*lhi;
  const float* xB = x + (size_t)rowB*512 + 8*lhi;
  const unsigned short* wHp = wtH + (size_t)l16*512 + 8*lhi;   // + f*16*512 per fragment
  const unsigned short* wLp = wtL + (size_t)l16*512 + 8*lhi;

  for (int k0 = 0; k0 < 512; k0 += 32) {
    float4 a0 = *(const float4*)(xA + k0);
    float4 a1v = *(const float4*)(xA + k0 + 4);
    float4 b0 = *(const float4*)(xB + k0);
    float4 b1v = *(const float4*)(xB + k0 + 4);
    bf16x8 bh[4], bl[4];
    #pragma unroll
    for (int f = 0; f < 4; ++f) {
      bh[f] = *(const bf16x8*)(wHp + (size_t)f*16*512 + k0);
      bl[f] = *(const bf16x8*)(wLp + (size_t)f*16*512 + k0);
    }
    bf16x8 ahA, alA, ahB, alB;
    split8(a0, a1v, ahA, alA);
    split8(b0, b1v, ahB, alB);
    #pragma unroll
    for (int f = 0; f < 4; ++f) {
      acc[0][f] = __builtin_amdgcn_mfma_f32_16x16x32_bf16(ahA, bh[f], acc[0][f], 0, 0, 0);
      acc[0][f] = __builtin_amdgcn_mfma_f32_16x16x32_bf16(ahA, bl[f], acc[0][f], 0, 0, 0);
      acc[0][f] = __builtin_amdgcn_mfma_f32_16x16x32_bf16(alA, bh[f], acc[0][f], 0, 0, 0);
      acc[1][f] = __builtin_amdgcn_mfma_f32_16x16x32_bf16(ahB, bh[f], acc[1][f], 0, 0, 0);
      acc[1][f] = __builtin_amdgcn_mfma_f32_16x16x32_bf16(ahB, bl[f], acc[1][f], 0, 0, 0);
      acc[1][f] = __builtin_amdgcn_mfma_f32_16x16x32_bf16(alB, bh[f], acc[1][f], 0, 0, 0);
    }
  }

  // epilogue: h1 (bf16) + per-head attention logit halves (fp32)
  #pragma unroll
  for (int m = 0; m < 2; ++m) {
    #pragma unroll
    for (int r = 0; r < 4; ++r) {
      int node = r0 + 16*m + 4*lhi + r;
      bool ok = (node < n);
      #pragma unroll
      for (int f = 0; f < 4; ++f) {
        float v = acc[m][f][r];
        if (ok) h1bf[(size_t)node*64 + 16*f + l16] = f2bf(v);
        float vs = v * as_c[f], vd = v * ad_c[f];
        vs += __shfl_xor(vs, 1); vs += __shfl_xor(vs, 2); vs += __shfl_xor(vs, 4);
        vd += __shfl_xor(vd, 1); vd += __shfl_xor(vd, 2); vd += __shfl_xor(vd, 4);
        if (ok && (l16 & 7) == 0) {
          int head = 2*f + (l16 >> 3);
          al1s[node*8 + head] = vs;
          al1d[node*8 + head] = vd;
        }
      }
    }
  }
}

// ---------------- layer 1 aggregation + ELU (4-deep pipelined, bf16 gather) ----------------
__global__ __launch_bounds__(256) void k_agg1(const int* __restrict__ ro,
    const int* __restrict__ csr, const float* __restrict__ al1s,
    const float* __restrict__ al1d, const unsigned short* __restrict__ h1bf,
    float* __restrict__ h1b, int n){
  int wid = blockIdx.x*4 + (threadIdx.x >> 6);
  if (wid >= n) return;
  int node = __builtin_amdgcn_readfirstlane(wid);
  int lane = threadIdx.x & 63;
  int h = lane >> 3;
  int beg = ro[node], end = ro[node+1];
  float ald = al1d[node*8 + h];
  float s = 0.f, acc = 0.f;
  if (beg < end) {
    int   srcb[4];
    float alb[4], hvb[4];
    #pragma unroll
    for (int j = 0; j < 4; ++j) {
      int idx = beg + j;
      srcb[j] = csr[idx < end ? idx : beg];
    }
    #pragma unroll
    for (int j = 0; j < 4; ++j) {
      alb[j] = al1s[srcb[j]*8 + h];
      hvb[j] = bf2f(h1bf[(size_t)srcb[j]*64 + lane]);
    }
    for (int t = beg; t < end; t += 4) {
      int   nsrc[4];
      float nal[4], nhv[4];
      #pragma unroll
      for (int j = 0; j < 4; ++j) {
        int idx = t + 4 + j;
        nsrc[j] = csr[idx < end ? idx : beg];
      }
      #pragma unroll
      for (int j = 0; j < 4; ++j) {
        nal[j] = al1s[nsrc[j]*8 + h];
        nhv[j] = bf2f(h1bf[(size_t)nsrc[j]*64 + lane]);
      }
      #pragma unroll
      for (int j = 0; j < 4; ++j) {
        float e = alb[j] + ald;
        e = e > 0.f ? e : NEG*e;
        float ex = (t + j < end) ? __expf(e) : 0.f;
        s += ex;
        acc = fmaf(hvb[j], ex, acc);
      }
      #pragma unroll
      for (int j = 0; j < 4; ++j) { srcb[j] = nsrc[j]; alb[j] = nal[j]; hvb[j] = nhv[j]; }
    }
  }
  float v = acc / (s + 1e-16f);
  v = v > 0.f ? v : expm1f(v);   // ELU
  h1b[(size_t)node*64 + lane] = v;
}

// ---------------- layer 2 projection (h2 stored bf16 for agg2 gather) ----------------
__global__ __launch_bounds__(256) void k_proj2(const float* __restrict__ h1b,
    const float* __restrict__ W2, const float* __restrict__ a2s_g, const float* __restrict__ a2d_g,
    unsigned short* __restrict__ h2bf, float* __restrict__ al2s, float* __restrict__ al2d, int n){
  __shared__ float w[64*16];
  __shared__ float a2sv[16], a2dv[16];
  for (int i = threadIdx.x; i < 1024; i += 256) w[i] = W2[i];
  if (threadIdx.x < 16) { a2sv[threadIdx.x] = a2s_g[threadIdx.x]; a2dv[threadIdx.x] = a2d_g[threadIdx.x]; }
  __syncthreads();
  int c = threadIdx.x & 15;
  int nid = blockIdx.x*16 + (threadIdx.x >> 4);
  if (nid >= n) return;
  const float* row = h1b + (size_t)nid*64;
  float acc = 0.f;
  #pragma unroll
  for (int k0 = 0; k0 < 64; k0 += 4) {
    float4 r = *(const float4*)(row + k0);
    acc = fmaf(r.x, w[(k0+0)*16 + c], acc);
    acc = fmaf(r.y, w[(k0+1)*16 + c], acc);
    acc = fmaf(r.z, w[(k0+2)*16 + c], acc);
    acc = fmaf(r.w, w[(k0+3)*16 + c], acc);
  }
  h2bf[(size_t)nid*16 + c] = f2bf(acc);
  float vs = acc * a2sv[c], vd = acc * a2dv[c];
  vs += __shfl_xor(vs, 1); vs += __shfl_xor(vs, 2); vs += __shfl_xor(vs, 4); vs += __shfl_xor(vs, 8);
  vd += __shfl_xor(vd, 1); vd += __shfl_xor(vd, 2); vd += __shfl_xor(vd, 4); vd += __shfl_xor(vd, 8);
  if (c == 0) { al2s[nid] = vs; al2d[nid] = vd; }
}

// ---------------- layer 2 aggregation + log_softmax (2-deep pipelined) ----------------
__global__ __launch_bounds__(256) void k_agg2(const int* __restrict__ ro,
    const int* __restrict__ csr, const float* __restrict__ al2s,
    const float* __restrict__ al2d, const unsigned short* __restrict__ h2bf,
    float* __restrict__ out, int n){
  int wid = blockIdx.x*4 + (threadIdx.x >> 6);
  if (wid >= n) return;
  int node = __builtin_amdgcn_readfirstlane(wid);
  int lane = threadIdx.x & 63;
  int j = lane >> 4, c = lane & 15;
  int beg = ro[node], end = ro[node+1];
  float ald = al2d[node];
  float sp = 0.f, acc = 0.f;
  if (beg < end) {
    int i = beg + j;
    int sA = csr[i < end ? i : beg];
    float aA = al2s[sA];
    float hA = bf2f(h2bf[(size_t)sA*16 + c]);
    for (; i < end; i += 4) {
      int i2 = i + 4;
      int sB = csr[i2 < end ? i2 : beg];
      float aB = al2s[sB];
      float hB = bf2f(h2bf[(size_t)sB*16 + c]);
      float e = lrelu(aA + ald);
      float ex = __expf(e);
      sp += ex;
      acc = fmaf(ex, hA, acc);
      sA = sB; aA = aB; hA = hB;
    }
  }
  sp  += __shfl_xor(sp, 16);  sp  += __shfl_xor(sp, 32);
  acc += __shfl_xor(acc, 16); acc += __shfl_xor(acc, 32);
  float v = acc / (sp + 1e-16f);
  float mx = v;
  mx = fmaxf(mx, __shfl_xor(mx, 1)); mx = fmaxf(mx, __shfl_xor(mx, 2));
  mx = fmaxf(mx, __shfl_xor(mx, 4)); mx = fmaxf(mx, __shfl_xor(mx, 8));
  float l = v - mx;
  float se = __expf(l);
  se += __shfl_xor(se, 1); se += __shfl_xor(se, 2);
  se += __shfl_xor(se, 4); se += __shfl_xor(se, 8);
  float res = l - logf(se);
  if (j == 0) out[(size_t)node*16 + c] = res;
}

// ---------------- host ----------------
static inline size_t alignup(size_t x){ return (x + 255) & ~(size_t)255; }

extern "C" void kernel_launch(void* const* d_in, const int* in_sizes, int n_in,
                              void* d_out, int out_size, void* d_ws, size_t ws_size,
                              hipStream_t stream){
  const float* x   = (const float*)d_in[0];
  const int*   ei  = (const int*)  d_in[1];
  const float* W1  = (const float*)d_in[2];
  const float* a1s = (const float*)d_in[3];
  const float* a1d = (const float*)d_in[4];
  const float* W2  = (const float*)d_in[5];
  const float* a2s = (const float*)d_in[6];
  const float* a2d = (const float*)d_in[7];
  float* out = (float*)d_out;

  const int n = in_sizes[0] / 512;   // 100000
  const int E = in_sizes[1] / 2;     // 3200000

  char* w = (char*)d_ws;
  unsigned short* h1bf = (unsigned short*)w; w += alignup((size_t)n*64*2);
  float* h1b  = (float*)w; w += alignup((size_t)n*64*4);
  float* al1s_ = (float*)w; w += alignup((size_t)n*8*4);
  float* al1d_ = (float*)w; w += alignup((size_t)n*8*4);
  unsigned short* h2bf = (unsigned short*)w; w += alignup((size_t)n*16*2);
  float* al2s_ = (float*)w; w += alignup((size_t)n*4);
  float* al2d_ = (float*)w; w += alignup((size_t)n*4);
  int* cnt    = (int*)w;   w += alignup((size_t)n*4);
  int* ro     = (int*)w;   w += alignup((size_t)(n+1)*4);
  int* cur    = (int*)w;   w += alignup((size_t)n*4);
  int* csr    = (int*)w;   w += alignup((size_t)E*4);
  int* bsum   = (int*)w;   w += alignup(512*4);
  int* flag   = (int*)w;   w += alignup(64);
  unsigned short* wtH = (unsigned short*)w; w += alignup(512*64*2);
  unsigned short* wtL = (unsigned short*)w; w += alignup(512*64*2);

  const int nb_scan = (n + 1023) / 1024;

  k_zero<<<(n+255)/256, 256, 0, stream>>>(cnt, n);
  k_flag<<<1, 64, 0, stream>>>(ei, flag);
  k_wprep<<<128, 256, 0, stream>>>(W1, wtH, wtL);
  k_count<<<(E+255)/256, 256, 0, stream>>>(ei, flag, cnt, E);
  k_scan1<<<nb_scan, 256, 0, stream>>>(cnt, ro, bsum, n);
  k_scan2<<<1, 64, 0, stream>>>(bsum, nb_scan);
  k_scan3<<<(n+255)/256, 256, 0, stream>>>(ro, cur, bsum, n, E);
  k_fill<<<2048, 256, 0, stream>>>(ei, flag, cur, csr, E, n);

  k_proj1<<<(n+127)/128, 256, 0, stream>>>(x, wtH, wtL, a1s, a1d, h1bf, al1s_, al1d_, n);
  k_agg1<<<(n+3)/4, 256, 0, stream>>>(ro, csr, al1s_, al1d_, h1bf, h1b, n);
  k_proj2<<<(n+15)/16, 256, 0, stream>>>(h1b, W2, a2s, a2d, h2bf, al2s_, al2d_, n);
  k_agg2<<<(n+3)/4, 256, 0, stream>>>(ro, csr, al2s_, al2d_, h2bf, out, n);
}